// Round 5
// baseline (2111.290 us; speedup 1.0000x reference)
//
#include <hip/hip_runtime.h>
#include <hip/hip_bf16.h>

#define NN 50000
#define EE 800000
#define TT 3
#define ED 64
#define NS 23
#define MD 87
#define HH 200
#define NMOL 2048
#define RD 256

#define BUF_S 228  // act buffer stride (u32): 228%32=4 -> conflict-free b128 pattern
#define AS_S 36    // streamed-A stride
#define LDS_WORDS (64 * BUF_S)  // 14592 u32 = 58368 B (2 blocks/CU of the 160KB pool)
#define NPB 64     // colstats partial blocks

typedef __attribute__((ext_vector_type(8))) short short8b;
typedef __attribute__((ext_vector_type(4))) float f32x4;

// ---- bf16 split helpers: value = hi + lo, each bf16 (RNE). ----
__device__ __forceinline__ unsigned short f2bf(float f) {
  unsigned u = __float_as_uint(f);
  return (unsigned short)((u + 0x7fffu + ((u >> 16) & 1u)) >> 16);
}
__device__ __forceinline__ float ubf2f(unsigned short h) {
  return __uint_as_float(((unsigned)h) << 16);
}
// interleaved pair in one u32: low16 = hi-bf16, high16 = lo-bf16
__device__ __forceinline__ float bfp2f(unsigned p) {
  return __uint_as_float(p << 16) + __uint_as_float(p & 0xffff0000u);
}
__device__ __forceinline__ unsigned packsplit(float v) {
  unsigned short h = f2bf(v);
  unsigned short l = f2bf(v - ubf2f(h));
  return (unsigned)h | ((unsigned)l << 16);
}
// 8 packed u32 -> hi-frag + lo-frag (short8b each) via v_perm
__device__ __forceinline__ void unpack8(const unsigned* v, short8b& h, short8b& l) {
  union { unsigned u[4]; short8b s; } H, L;
#pragma unroll
  for (int e = 0; e < 4; e++) {
    H.u[e] = __builtin_amdgcn_perm(v[2 * e + 1], v[2 * e], 0x05040100u);
    L.u[e] = __builtin_amdgcn_perm(v[2 * e + 1], v[2 * e], 0x07060302u);
  }
  h = H.s;
  l = L.s;
}

// ---------------- weight prep: fp32 [T][K][N] -> u32-pair [T][Npad][Kpad] (transposed) ----
struct WD { const float* src; unsigned* dst; int K, N, Kpad, Npad, T; };
struct WDs { WD d[7]; };

__global__ __launch_bounds__(256) void wprep_kernel(WDs W) {
  WD w = W.d[blockIdx.y];
  int per = w.Npad * w.Kpad;
  int total = w.T * per;
  for (int idx = blockIdx.x * 256 + threadIdx.x; idx < total; idx += gridDim.x * 256) {
    int t = idx / per;
    int r = idx - t * per;
    int n = r / w.Kpad;
    int k = r - n * w.Kpad;
    unsigned v = 0;
    if (k < w.K && n < w.N) v = packsplit(w.src[((size_t)t * w.K + k) * w.N + n]);
    w.dst[idx] = v;
  }
}

// ---------------- embedding -> x slice 0 ----------------
__global__ __launch_bounds__(256) void emb_kernel(const int* __restrict__ z,
                                                  const float* __restrict__ emb,
                                                  unsigned* __restrict__ xp) {
  int idx = blockIdx.x * 256 + threadIdx.x;
  if (idx >= NN * ED) return;
  int i = idx >> 6, d = idx & 63;
  xp[(size_t)i * RD + d] = packsplit(emb[z[i] * ED + d]);
}

// ---------------- CSR build ----------------
__global__ __launch_bounds__(256) void hist_kernel(const int* __restrict__ src,
                                                   int* __restrict__ deg) {
  int e = blockIdx.x * 256 + threadIdx.x;
  if (e < EE) atomicAdd(&deg[src[e]], 1);
}

__global__ __launch_bounds__(1024) void scan_kernel(const int* __restrict__ deg,
                                                    int* __restrict__ offs,
                                                    int* __restrict__ cursor) {
  __shared__ int sh[1024];
  int tid = threadIdx.x;
  const int CH = (NN + 1023) / 1024;
  int s0 = tid * CH, s1 = s0 + CH;
  if (s1 > NN) s1 = NN;
  int sum = 0;
  for (int i = s0; i < s1; i++) sum += deg[i];
  sh[tid] = sum;
  __syncthreads();
  for (int off = 1; off < 1024; off <<= 1) {
    int t = (tid >= off) ? sh[tid - off] : 0;
    __syncthreads();
    sh[tid] += t;
    __syncthreads();
  }
  int base = sh[tid] - sum;
  for (int i = s0; i < s1; i++) {
    offs[i] = base;
    cursor[i] = base;
    base += deg[i];
  }
  if (tid == 1023) offs[NN] = sh[1023];
}

__global__ __launch_bounds__(256) void scatter_kernel(const int* __restrict__ src,
                                                      const int* __restrict__ snk,
                                                      const float* __restrict__ dist,
                                                      int* __restrict__ cursor,
                                                      int* __restrict__ ssink,
                                                      float* __restrict__ sdist) {
  int e = blockIdx.x * 256 + threadIdx.x;
  if (e >= EE) return;
  int p = atomicAdd(&cursor[src[e]], 1);
  ssink[p] = snk[e];
  sdist[p] = dist[e];
}

// ---------------- message gather: one wave per node ----------------
__global__ __launch_bounds__(256) void gather_kernel(const int* __restrict__ offs,
                                                     const int* __restrict__ ssink,
                                                     const float* __restrict__ sdist,
                                                     const unsigned* __restrict__ xp,
                                                     int toff, unsigned* __restrict__ m) {
  int node = blockIdx.x * 4 + (threadIdx.x >> 6);
  int lane = threadIdx.x & 63;
  if (node >= NN) return;
  float shift = (float)(0.8 + 0.1 * (double)lane);
  float accx = 0.f, accr = 0.f;
  int e0 = offs[node], e1 = offs[node + 1];
  for (int j = e0; j < e1; ++j) {
    int s = ssink[j];
    accx += bfp2f(xp[(size_t)s * RD + toff + lane]);
    if (lane < NS) {
      float u = sdist[j] - shift;
      accr += __expf(-u * u);
    }
  }
  if (lane < NS) m[node * 96 + lane] = packsplit(accr);
  m[node * 96 + NS + lane] = packsplit(accx);
}

// ---------------- batchnorm stats ----------------
template <int LD>
__global__ __launch_bounds__(256) void colstats_kernel(const unsigned* __restrict__ X,
                                                       int ncols, float* __restrict__ P) {
  int c = threadIdx.x;
  float s = 0.f, q = 0.f;
  if (c < ncols) {
    for (int r = blockIdx.x; r < NN; r += gridDim.x) {
      float v = bfp2f(X[(size_t)r * LD + c]);
      s += v;
      q += v * v;
    }
  }
  P[blockIdx.x * 512 + c] = s;
  P[blockIdx.x * 512 + 256 + c] = q;
}

__global__ __launch_bounds__(256) void bnfinal_kernel(const float* __restrict__ P, int nblk,
                                                      const float* __restrict__ g,
                                                      const float* __restrict__ b, int ncols,
                                                      float* __restrict__ na,
                                                      float* __restrict__ nb) {
  int c = threadIdx.x;
  float s = 0.f, q = 0.f;
  for (int i = 0; i < nblk; i++) {
    s += P[i * 512 + c];
    q += P[i * 512 + 256 + c];
  }
  if (c < ncols) {
    float mean = s / (float)NN;
    float var = q / (float)NN - mean * mean;
    float a = g[c] * rsqrtf(var + 1e-5f);
    na[c] = a;
    nb[c] = b[c] - mean * a;
  } else {
    na[c] = 0.f;  // zero-pad: BN at staging then zeroes pad columns automatically
    nb[c] = 0.f;
  }
}

// ---------------- fused MLP kernel ----------------
// 64-node tile per block, 512 threads = 8 waves in a 2(M) x 4(N) grid ->
// 16 waves/CU at 2 blocks/CU (vs 8 in R4: latency-bound fix).
// All layers keep activations resident in LDS (pair format); B (weight)
// fragments read directly from global (L2-resident) -> no barriers in
// buf0-sourced K-loops. Split-precision: 3 MFMA (hh,hl,lh) = fp32-equivalent.
template <bool READOUT>
__global__ __launch_bounds__(512, 4) void fused_kernel(
    const unsigned* __restrict__ Asrc, int astride,
    const float* __restrict__ na, const float* __restrict__ nb,
    const unsigned* __restrict__ W1t, const unsigned* __restrict__ W2t,
    const unsigned* __restrict__ W3t, const unsigned* __restrict__ W4t,
    const float* __restrict__ b1, const float* __restrict__ b2,
    const float* __restrict__ b3, const float* __restrict__ b4,
    unsigned* __restrict__ xp, int t,
    const float* __restrict__ w4ro, const int* __restrict__ mol,
    float* __restrict__ out) {
  __shared__ unsigned lds[LDS_WORDS];
  unsigned* buf0 = lds;  // 64 x BUF_S activation pair
  unsigned* As = lds;    // streamed-A double buffer 2 x 64 x AS_S = 4608 words (alias ok)

  const int tid = threadIdx.x;
  const int wave = tid >> 6, lane = tid & 63, ln = lane & 15, quad = lane >> 4;
  const int wm = wave & 1;        // M half: rows wm*32 .. wm*32+31
  const int wn = wave >> 1;       // N quarter
  const int bm = blockIdx.x * 64;

  const int ntile = (wn == 0) ? 4 : 3;
  const int n0col = (wn == 0) ? 0 : 16 + wn * 48;  // 0, 64, 112, 160

  f32x4 acc[2][4];

  auto run_layer = [&](const unsigned* __restrict__ Wt, int Kpad, int KP, bool streamA) {
#pragma unroll
    for (int i = 0; i < 2; i++)
#pragma unroll
      for (int j = 0; j < 4; j++) acc[i][j] = (f32x4){0.f, 0.f, 0.f, 0.f};

    int parity = 0;
    for (int k0 = 0; k0 < KP; k0 += 32, parity ^= 1) {
      if (streamA) {
        unsigned* Asb = As + parity * (64 * AS_S);
        int row = tid >> 3, seg = (tid & 7) * 4;
        int grow = bm + row;
        unsigned tmp[4];
        if (grow < NN) {
          *(uint4*)&tmp[0] = *(const uint4*)(Asrc + (size_t)grow * astride + k0 + seg);
        } else {
#pragma unroll
          for (int e = 0; e < 4; e++) tmp[e] = 0;
        }
#pragma unroll
        for (int e = 0; e < 4; e++) {
          int k = k0 + seg + e;
          tmp[e] = packsplit(bfp2f(tmp[e]) * na[k] + nb[k]);
        }
        *(uint4*)(Asb + row * AS_S + seg) = *(uint4*)&tmp[0];
        __syncthreads();
      }
      // ---- A fragments (LDS) ----
      short8b ah[2], al[2];
#pragma unroll
      for (int i = 0; i < 2; i++) {
        int r = wm * 32 + i * 16 + ln;
        const unsigned* ap = streamA ? (As + parity * (64 * AS_S) + r * AS_S + quad * 8)
                                     : (buf0 + r * BUF_S + k0 + quad * 8);
        unsigned v[8];
        *(uint4*)&v[0] = *(const uint4*)ap;
        *(uint4*)&v[4] = *(const uint4*)(ap + 4);
        unpack8(v, ah[i], al[i]);
      }
      // ---- B fragments (global, L2-hot) + MFMA ----
#pragma unroll
      for (int j = 0; j < 4; j++) {
        if (j < ntile) {
          int n = n0col + j * 16 + ln;
          const unsigned* bp = Wt + (size_t)n * Kpad + k0 + quad * 8;
          unsigned v[8];
          *(uint4*)&v[0] = *(const uint4*)bp;
          *(uint4*)&v[4] = *(const uint4*)(bp + 4);
          short8b bh, bl;
          unpack8(v, bh, bl);
#pragma unroll
          for (int i = 0; i < 2; i++) {
            acc[i][j] = __builtin_amdgcn_mfma_f32_16x16x32_bf16(ah[i], bh, acc[i][j], 0, 0, 0);
            acc[i][j] = __builtin_amdgcn_mfma_f32_16x16x32_bf16(ah[i], bl, acc[i][j], 0, 0, 0);
            acc[i][j] = __builtin_amdgcn_mfma_f32_16x16x32_bf16(al[i], bh, acc[i][j], 0, 0, 0);
          }
        }
      }
    }
  };

  // epilogue: relu(acc+bias) -> buf0; waves 6,7 zero-fill pad cols [208,224)
  auto epi = [&](const float* __restrict__ bias) {
    __syncthreads();  // all frag reads of buf0/As complete before overwrite
#pragma unroll
    for (int i = 0; i < 2; i++)
#pragma unroll
      for (int j = 0; j < 4; j++) {
        if (j < ntile) {
#pragma unroll
          for (int r = 0; r < 4; r++) {
            int row = wm * 32 + i * 16 + quad * 4 + r;
            int col = n0col + j * 16 + ln;
            float v = acc[i][j][r] + (col < HH ? bias[col] : 0.f);
            v = fmaxf(v, 0.f);
            buf0[row * BUF_S + col] = packsplit(v);
          }
        }
      }
    if (wave >= 6) {  // wave6 rows 0..31, wave7 rows 32..63
      int rbase = (wave & 1) * 32 + quad * 8;
#pragma unroll
      for (int rr = 0; rr < 8; rr++) buf0[(rbase + rr) * BUF_S + 208 + ln] = 0u;
    }
    __syncthreads();
  };

  if (!READOUT) {
    run_layer(W1t, 96, 96, true);
    epi(b1);
    run_layer(W2t, 224, 224, false);
    epi(b2);
    run_layer(W3t, 224, 224, false);
    epi(b3);
    // ---- L4 (200->64): wave w handles col tile (w>>1)*16, row half (w&1)*32 ----
#pragma unroll
    for (int i = 0; i < 2; i++) acc[i][0] = (f32x4){0.f, 0.f, 0.f, 0.f};
    const int ct = wn;  // col tile 0..3
    for (int k0 = 0; k0 < 224; k0 += 32) {
      short8b ah[2], al[2];
#pragma unroll
      for (int i = 0; i < 2; i++) {
        int r = wm * 32 + i * 16 + ln;
        const unsigned* ap = buf0 + r * BUF_S + k0 + quad * 8;
        unsigned v[8];
        *(uint4*)&v[0] = *(const uint4*)ap;
        *(uint4*)&v[4] = *(const uint4*)(ap + 4);
        unpack8(v, ah[i], al[i]);
      }
      int n = ct * 16 + ln;
      const unsigned* bp = W4t + (size_t)n * 224 + k0 + quad * 8;
      unsigned v[8];
      *(uint4*)&v[0] = *(const uint4*)bp;
      *(uint4*)&v[4] = *(const uint4*)(bp + 4);
      short8b bh, bl;
      unpack8(v, bh, bl);
#pragma unroll
      for (int i = 0; i < 2; i++) {
        acc[i][0] = __builtin_amdgcn_mfma_f32_16x16x32_bf16(ah[i], bh, acc[i][0], 0, 0, 0);
        acc[i][0] = __builtin_amdgcn_mfma_f32_16x16x32_bf16(ah[i], bl, acc[i][0], 0, 0, 0);
        acc[i][0] = __builtin_amdgcn_mfma_f32_16x16x32_bf16(al[i], bh, acc[i][0], 0, 0, 0);
      }
    }
    // x-update epilogue: x[t+1] = x[t] + 0.1*(h3@W4 + b4)  (global only, no sync)
#pragma unroll
    for (int i = 0; i < 2; i++)
#pragma unroll
      for (int r = 0; r < 4; r++) {
        int grow = bm + wm * 32 + i * 16 + quad * 4 + r;
        int col = ct * 16 + ln;
        if (grow < NN) {
          float v = acc[i][0][r] + b4[col];
          size_t base = (size_t)grow * RD;
          float old = bfp2f(xp[base + (size_t)t * ED + col]);
          xp[base + (size_t)(t + 1) * ED + col] = packsplit(old + 0.1f * v);
        }
      }
  } else {
    run_layer(W1t, 256, 256, true);
    epi(b1);
    run_layer(W2t, 224, 224, false);
    epi(b2);
    run_layer(W3t, 224, 224, false);
    epi(b3);
    // fused final layer (200->1) + molecule segment-sum: 8 threads per row
    int row = tid >> 3;
    int grow = bm + row;
    float s = 0.f;
    for (int c = (tid & 7); c < HH; c += 8) s += bfp2f(buf0[row * BUF_S + c]) * w4ro[c];
    s += __shfl_xor(s, 1, 64);
    s += __shfl_xor(s, 2, 64);
    s += __shfl_xor(s, 4, 64);
    if ((tid & 7) == 0 && grow < NN) atomicAdd(&out[mol[grow]], s + b4[0]);
  }
}

// ---------------- host launcher ----------------
extern "C" void kernel_launch(void* const* d_in, const int* in_sizes, int n_in,
                              void* d_out, int out_size, void* d_ws, size_t ws_size,
                              hipStream_t stream) {
  const int* z_i = (const int*)d_in[0];
  const int* e_src = (const int*)d_in[1];
  const int* e_snk = ((const int*)d_in[1]) + EE;
  const float* dist = (const float*)d_in[2];
  const int* mol = (const int*)d_in[3];
  const float* emb = (const float*)d_in[4];
  const float* up_bn_g = (const float*)d_in[5];
  const float* up_bn_b = (const float*)d_in[6];
  const float* up_w1 = (const float*)d_in[7];
  const float* up_b1 = (const float*)d_in[8];
  const float* up_w2 = (const float*)d_in[9];
  const float* up_b2 = (const float*)d_in[10];
  const float* up_w3 = (const float*)d_in[11];
  const float* up_b3 = (const float*)d_in[12];
  const float* up_w4 = (const float*)d_in[13];
  const float* up_b4 = (const float*)d_in[14];
  const float* ro_bn_g = (const float*)d_in[15];
  const float* ro_bn_b = (const float*)d_in[16];
  const float* ro_w1 = (const float*)d_in[17];
  const float* ro_b1 = (const float*)d_in[18];
  const float* ro_w2 = (const float*)d_in[19];
  const float* ro_b2 = (const float*)d_in[20];
  const float* ro_w3 = (const float*)d_in[21];
  const float* ro_b3 = (const float*)d_in[22];
  const float* ro_w4 = (const float*)d_in[23];
  const float* ro_b4 = (const float*)d_in[24];
  float* out = (float*)d_out;

  char* p = (char*)d_ws;
  auto alloc = [&](size_t bytes) {
    void* r = (void*)p;
    p += (bytes + 255) & ~(size_t)255;
    return r;
  };
  unsigned* x_p = (unsigned*)alloc((size_t)NN * RD * 4);   // 51.2 MB
  unsigned* m_p = (unsigned*)alloc((size_t)NN * 96 * 4);   // 19.2 MB
  int* ssink = (int*)alloc((size_t)EE * 4);
  float* sdist = (float*)alloc((size_t)EE * 4);
  int* offs = (int*)alloc((size_t)(NN + 1) * 4);
  int* deg = (int*)alloc((size_t)NN * 4);
  int* cursor = (int*)alloc((size_t)NN * 4);
  float* P = (float*)alloc((size_t)NPB * 512 * 4);
  float* na = (float*)alloc(256 * 4);
  float* nb = (float*)alloc(256 * 4);
  // transposed/padded pair weights
  unsigned* w1t = (unsigned*)alloc((size_t)TT * 208 * 96 * 4);
  unsigned* w2t = (unsigned*)alloc((size_t)TT * 208 * 224 * 4);
  unsigned* w3t = (unsigned*)alloc((size_t)TT * 208 * 224 * 4);
  unsigned* w4t = (unsigned*)alloc((size_t)TT * 64 * 224 * 4);
  unsigned* r1t = (unsigned*)alloc((size_t)208 * 256 * 4);
  unsigned* r2t = (unsigned*)alloc((size_t)208 * 224 * 4);
  unsigned* r3t = (unsigned*)alloc((size_t)208 * 224 * 4);

  hipMemsetAsync(deg, 0, (size_t)NN * 4, stream);
  hipMemsetAsync(out, 0, (size_t)NMOL * 4, stream);

  WDs descs;
  descs.d[0] = {up_w1, w1t, MD, HH, 96, 208, TT};
  descs.d[1] = {up_w2, w2t, HH, HH, 224, 208, TT};
  descs.d[2] = {up_w3, w3t, HH, HH, 224, 208, TT};
  descs.d[3] = {up_w4, w4t, HH, ED, 224, 64, TT};
  descs.d[4] = {ro_w1, r1t, RD, HH, 256, 208, 1};
  descs.d[5] = {ro_w2, r2t, HH, HH, 224, 208, 1};
  descs.d[6] = {ro_w3, r3t, HH, HH, 224, 208, 1};
  wprep_kernel<<<dim3(273, 7), 256, 0, stream>>>(descs);

  emb_kernel<<<(NN * ED + 255) / 256, 256, 0, stream>>>(z_i, emb, x_p);
  hist_kernel<<<(EE + 255) / 256, 256, 0, stream>>>(e_src, deg);
  scan_kernel<<<1, 1024, 0, stream>>>(deg, offs, cursor);
  scatter_kernel<<<(EE + 255) / 256, 256, 0, stream>>>(e_src, e_snk, dist, cursor, ssink, sdist);

  const int gM = (NN + 63) / 64;  // 782

  for (int t = 0; t < TT; t++) {
    gather_kernel<<<(NN + 3) / 4, 256, 0, stream>>>(offs, ssink, sdist, x_p, t * ED, m_p);
    colstats_kernel<96><<<NPB, 256, 0, stream>>>(m_p, MD, P);
    bnfinal_kernel<<<1, 256, 0, stream>>>(P, NPB, up_bn_g + t * MD, up_bn_b + t * MD, MD, na, nb);
    fused_kernel<false><<<gM, 512, 0, stream>>>(
        m_p, 96, na, nb,
        w1t + (size_t)t * 208 * 96, w2t + (size_t)t * 208 * 224,
        w3t + (size_t)t * 208 * 224, w4t + (size_t)t * 64 * 224,
        up_b1 + t * HH, up_b2 + t * HH, up_b3 + t * HH, up_b4 + t * ED,
        x_p, t, nullptr, nullptr, nullptr);
  }

  colstats_kernel<256><<<NPB, 256, 0, stream>>>(x_p, RD, P);
  bnfinal_kernel<<<1, 256, 0, stream>>>(P, NPB, ro_bn_g, ro_bn_b, RD, na, nb);
  fused_kernel<true><<<gM, 512, 0, stream>>>(
      x_p, 256, na, nb,
      r1t, r2t, r3t, nullptr,
      ro_b1, ro_b2, ro_b3, ro_b4,
      nullptr, 0, ro_w4, mol, out);

  (void)in_sizes; (void)n_in; (void)out_size; (void)ws_size;
}

// Round 6
// 1234.707 us; speedup vs baseline: 1.7100x; 1.7100x over previous
//
#include <hip/hip_runtime.h>
#include <hip/hip_bf16.h>

#define NN 50000
#define EE 800000
#define TT 3
#define ED 64
#define NS 23
#define MD 87
#define HH 200
#define NMOL 2048
#define RD 256

#define BUF_S 228  // act buffer stride (u32): conflict-free b128 pattern
#define AS_S 36    // streamed-A stride
#define LDS_WORDS (64 * BUF_S)  // 14592 u32 = 58368 B (2 blocks/CU of the 160KB pool)
#define NPB2 512   // colstats partial blocks (latency fix: 512 blocks x vectorized rows)

typedef __attribute__((ext_vector_type(8))) short short8b;
typedef __attribute__((ext_vector_type(4))) float f32x4;

// ---- bf16 split helpers: value = hi + lo, each bf16 (RNE). ----
__device__ __forceinline__ unsigned short f2bf(float f) {
  unsigned u = __float_as_uint(f);
  return (unsigned short)((u + 0x7fffu + ((u >> 16) & 1u)) >> 16);
}
__device__ __forceinline__ float ubf2f(unsigned short h) {
  return __uint_as_float(((unsigned)h) << 16);
}
// interleaved pair in one u32: low16 = hi-bf16, high16 = lo-bf16
__device__ __forceinline__ float bfp2f(unsigned p) {
  return __uint_as_float(p << 16) + __uint_as_float(p & 0xffff0000u);
}
__device__ __forceinline__ unsigned packsplit(float v) {
  unsigned short h = f2bf(v);
  unsigned short l = f2bf(v - ubf2f(h));
  return (unsigned)h | ((unsigned)l << 16);
}
// 8 packed u32 -> hi-frag + lo-frag (short8b each) via v_perm
__device__ __forceinline__ void unpack8(const unsigned* v, short8b& h, short8b& l) {
  union { unsigned u[4]; short8b s; } H, L;
#pragma unroll
  for (int e = 0; e < 4; e++) {
    H.u[e] = __builtin_amdgcn_perm(v[2 * e + 1], v[2 * e], 0x05040100u);
    L.u[e] = __builtin_amdgcn_perm(v[2 * e + 1], v[2 * e], 0x07060302u);
  }
  h = H.s;
  l = L.s;
}

// ---------------- weight prep: fp32 [T][K][N] -> u32-pair [T][Npad][Kpad] (transposed) ----
struct WD { const float* src; unsigned* dst; int K, N, Kpad, Npad, T; };
struct WDs { WD d[7]; };

__global__ __launch_bounds__(256) void wprep_kernel(WDs W) {
  WD w = W.d[blockIdx.y];
  int per = w.Npad * w.Kpad;
  int total = w.T * per;
  for (int idx = blockIdx.x * 256 + threadIdx.x; idx < total; idx += gridDim.x * 256) {
    int t = idx / per;
    int r = idx - t * per;
    int n = r / w.Kpad;
    int k = r - n * w.Kpad;
    unsigned v = 0;
    if (k < w.K && n < w.N) v = packsplit(w.src[((size_t)t * w.K + k) * w.N + n]);
    w.dst[idx] = v;
  }
}

// ---------------- embedding -> x slice 0 ----------------
__global__ __launch_bounds__(256) void emb_kernel(const int* __restrict__ z,
                                                  const float* __restrict__ emb,
                                                  unsigned* __restrict__ xp) {
  int idx = blockIdx.x * 256 + threadIdx.x;
  if (idx >= NN * ED) return;
  int i = idx >> 6, d = idx & 63;
  xp[(size_t)i * RD + d] = packsplit(emb[z[i] * ED + d]);
}

// ---------------- CSR build ----------------
__global__ __launch_bounds__(256) void hist_kernel(const int* __restrict__ src,
                                                   int* __restrict__ deg) {
  int e = blockIdx.x * 256 + threadIdx.x;
  if (e < EE) atomicAdd(&deg[src[e]], 1);
}

__global__ __launch_bounds__(1024) void scan_kernel(const int* __restrict__ deg,
                                                    int* __restrict__ offs,
                                                    int* __restrict__ cursor) {
  __shared__ int sh[1024];
  int tid = threadIdx.x;
  const int CH = (NN + 1023) / 1024;
  int s0 = tid * CH, s1 = s0 + CH;
  if (s1 > NN) s1 = NN;
  int sum = 0;
  for (int i = s0; i < s1; i++) sum += deg[i];
  sh[tid] = sum;
  __syncthreads();
  for (int off = 1; off < 1024; off <<= 1) {
    int t = (tid >= off) ? sh[tid - off] : 0;
    __syncthreads();
    sh[tid] += t;
    __syncthreads();
  }
  int base = sh[tid] - sum;
  for (int i = s0; i < s1; i++) {
    offs[i] = base;
    cursor[i] = base;
    base += deg[i];
  }
  if (tid == 1023) offs[NN] = sh[1023];
}

__global__ __launch_bounds__(256) void scatter_kernel(const int* __restrict__ src,
                                                      const int* __restrict__ snk,
                                                      const float* __restrict__ dist,
                                                      int* __restrict__ cursor,
                                                      int* __restrict__ ssink,
                                                      float* __restrict__ sdist) {
  int e = blockIdx.x * 256 + threadIdx.x;
  if (e >= EE) return;
  int p = atomicAdd(&cursor[src[e]], 1);
  ssink[p] = snk[e];
  sdist[p] = dist[e];
}

// ---------------- message gather: one wave per node ----------------
__global__ __launch_bounds__(256) void gather_kernel(const int* __restrict__ offs,
                                                     const int* __restrict__ ssink,
                                                     const float* __restrict__ sdist,
                                                     const unsigned* __restrict__ xp,
                                                     int toff, unsigned* __restrict__ m) {
  int node = blockIdx.x * 4 + (threadIdx.x >> 6);
  int lane = threadIdx.x & 63;
  if (node >= NN) return;
  float shift = (float)(0.8 + 0.1 * (double)lane);
  float accx = 0.f, accr = 0.f;
  int e0 = offs[node], e1 = offs[node + 1];
  for (int j = e0; j < e1; ++j) {
    int s = ssink[j];
    accx += bfp2f(xp[(size_t)s * RD + toff + lane]);
    if (lane < NS) {
      float u = sdist[j] - shift;
      accr += __expf(-u * u);
    }
  }
  if (lane < NS) m[node * 96 + lane] = packsplit(accr);
  m[node * 96 + NS + lane] = packsplit(accx);
}

// ---------------- batchnorm stats: stage 1 (vectorized, 512 blocks) ----------
// Thread t owns 4-column group cg = t%CG, row-slot rin = t/CG; rows split over
// (blocks x RPB). uint4 loads; LDS tree over row-slots; P[b*512+c]=sum,
// P[b*512+256+c]=sumsq. Pad columns carry garbage -> ignored in stage 2.
template <int LD>
__global__ __launch_bounds__(256) void colstats2_kernel(const unsigned* __restrict__ X,
                                                        float* __restrict__ P) {
  constexpr int CG = LD / 4;
  constexpr int RPB = 256 / CG;
  const int t = threadIdx.x;
  const int cg = t % CG, rin = t / CG;
  float s0 = 0, s1 = 0, s2 = 0, s3 = 0, q0 = 0, q1 = 0, q2 = 0, q3 = 0;
  if (rin < RPB) {
    for (int r = blockIdx.x * RPB + rin; r < NN; r += gridDim.x * RPB) {
      uint4 v = *(const uint4*)(X + (size_t)r * LD + cg * 4);
      float f0 = bfp2f(v.x), f1 = bfp2f(v.y), f2 = bfp2f(v.z), f3 = bfp2f(v.w);
      s0 += f0; q0 += f0 * f0;
      s1 += f1; q1 += f1 * f1;
      s2 += f2; q2 += f2 * f2;
      s3 += f3; q3 += f3 * f3;
    }
  }
  __shared__ float sh[256][8];
  sh[t][0] = s0; sh[t][1] = s1; sh[t][2] = s2; sh[t][3] = s3;
  sh[t][4] = q0; sh[t][5] = q1; sh[t][6] = q2; sh[t][7] = q3;
  __syncthreads();
  if (rin == 0) {
#pragma unroll
    for (int rr = 1; rr < RPB; rr++) {
      const float* o = sh[rr * CG + cg];
      s0 += o[0]; s1 += o[1]; s2 += o[2]; s3 += o[3];
      q0 += o[4]; q1 += o[5]; q2 += o[6]; q3 += o[7];
    }
    float* Pb = P + blockIdx.x * 512;
    Pb[cg * 4 + 0] = s0; Pb[cg * 4 + 1] = s1; Pb[cg * 4 + 2] = s2; Pb[cg * 4 + 3] = s3;
    Pb[256 + cg * 4 + 0] = q0; Pb[256 + cg * 4 + 1] = q1;
    Pb[256 + cg * 4 + 2] = q2; Pb[256 + cg * 4 + 3] = q3;
  }
}

// ---------------- batchnorm stats: stage 2 (one block per column) ------------
__global__ __launch_bounds__(256) void bnfinal2_kernel(const float* __restrict__ P, int nblk,
                                                       const float* __restrict__ g,
                                                       const float* __restrict__ b, int ncols,
                                                       float* __restrict__ na,
                                                       float* __restrict__ nb) {
  int c = blockIdx.x;
  int t = threadIdx.x;
  float s = 0.f, q = 0.f;
  for (int i = t; i < nblk; i += 256) {
    s += P[i * 512 + c];
    q += P[i * 512 + 256 + c];
  }
#pragma unroll
  for (int off = 32; off > 0; off >>= 1) {
    s += __shfl_down(s, off, 64);
    q += __shfl_down(q, off, 64);
  }
  __shared__ float ws[4], wq[4];
  if ((t & 63) == 0) { ws[t >> 6] = s; wq[t >> 6] = q; }
  __syncthreads();
  if (t == 0) {
    s = ws[0] + ws[1] + ws[2] + ws[3];
    q = wq[0] + wq[1] + wq[2] + wq[3];
    if (c < ncols) {
      float mean = s / (float)NN;
      float var = q / (float)NN - mean * mean;
      float a = g[c] * rsqrtf(var + 1e-5f);
      na[c] = a;
      nb[c] = b[c] - mean * a;
    } else {
      na[c] = 0.f;  // zero-pad: BN at staging then zeroes pad columns automatically
      nb[c] = 0.f;
    }
  }
}

// ---------------- fused MLP kernel ----------------
// 64-node tile per block, 512 threads = 8 waves in a 2(M) x 4(N) grid ->
// 16 waves/CU at 2 blocks/CU. Activations LDS-resident (pair format); B
// fragments read directly from global (L2-resident) -> no barriers in
// buf0-sourced K-loops. Split-precision: 3 MFMA (hh,hl,lh) = fp32-equivalent.
template <bool READOUT>
__global__ __launch_bounds__(512, 4) void fused_kernel(
    const unsigned* __restrict__ Asrc, int astride,
    const float* __restrict__ na, const float* __restrict__ nb,
    const unsigned* __restrict__ W1t, const unsigned* __restrict__ W2t,
    const unsigned* __restrict__ W3t, const unsigned* __restrict__ W4t,
    const float* __restrict__ b1, const float* __restrict__ b2,
    const float* __restrict__ b3, const float* __restrict__ b4,
    unsigned* __restrict__ xp, int t,
    const float* __restrict__ w4ro, const int* __restrict__ mol,
    float* __restrict__ out) {
  __shared__ unsigned lds[LDS_WORDS];
  unsigned* buf0 = lds;  // 64 x BUF_S activation pair
  unsigned* As = lds;    // streamed-A double buffer 2 x 64 x AS_S = 4608 words (alias ok)

  const int tid = threadIdx.x;
  const int wave = tid >> 6, lane = tid & 63, ln = lane & 15, quad = lane >> 4;
  const int wm = wave & 1;   // M half: rows wm*32 .. wm*32+31
  const int wn = wave >> 1;  // N quarter
  const int bm = blockIdx.x * 64;

  const int ntile = (wn == 0) ? 4 : 3;
  const int n0col = (wn == 0) ? 0 : 16 + wn * 48;  // 0, 64, 112, 160

  f32x4 acc[2][4];

  auto run_layer = [&](const unsigned* __restrict__ Wt, int Kpad, int KP, bool streamA) {
#pragma unroll
    for (int i = 0; i < 2; i++)
#pragma unroll
      for (int j = 0; j < 4; j++) acc[i][j] = (f32x4){0.f, 0.f, 0.f, 0.f};

    int parity = 0;
    for (int k0 = 0; k0 < KP; k0 += 32, parity ^= 1) {
      if (streamA) {
        unsigned* Asb = As + parity * (64 * AS_S);
        int row = tid >> 3, seg = (tid & 7) * 4;
        int grow = bm + row;
        unsigned tmp[4];
        if (grow < NN) {
          *(uint4*)&tmp[0] = *(const uint4*)(Asrc + (size_t)grow * astride + k0 + seg);
        } else {
#pragma unroll
          for (int e = 0; e < 4; e++) tmp[e] = 0;
        }
#pragma unroll
        for (int e = 0; e < 4; e++) {
          int k = k0 + seg + e;
          tmp[e] = packsplit(bfp2f(tmp[e]) * na[k] + nb[k]);
        }
        *(uint4*)(Asb + row * AS_S + seg) = *(uint4*)&tmp[0];
        __syncthreads();
      }
      // ---- A fragments (LDS) ----
      short8b ah[2], al[2];
#pragma unroll
      for (int i = 0; i < 2; i++) {
        int r = wm * 32 + i * 16 + ln;
        const unsigned* ap = streamA ? (As + parity * (64 * AS_S) + r * AS_S + quad * 8)
                                     : (buf0 + r * BUF_S + k0 + quad * 8);
        unsigned v[8];
        *(uint4*)&v[0] = *(const uint4*)ap;
        *(uint4*)&v[4] = *(const uint4*)(ap + 4);
        unpack8(v, ah[i], al[i]);
      }
      // ---- B fragments (global, L2-hot) + MFMA ----
#pragma unroll
      for (int j = 0; j < 4; j++) {
        if (j < ntile) {
          int n = n0col + j * 16 + ln;
          const unsigned* bp = Wt + (size_t)n * Kpad + k0 + quad * 8;
          unsigned v[8];
          *(uint4*)&v[0] = *(const uint4*)bp;
          *(uint4*)&v[4] = *(const uint4*)(bp + 4);
          short8b bh, bl;
          unpack8(v, bh, bl);
#pragma unroll
          for (int i = 0; i < 2; i++) {
            acc[i][j] = __builtin_amdgcn_mfma_f32_16x16x32_bf16(ah[i], bh, acc[i][j], 0, 0, 0);
            acc[i][j] = __builtin_amdgcn_mfma_f32_16x16x32_bf16(ah[i], bl, acc[i][j], 0, 0, 0);
            acc[i][j] = __builtin_amdgcn_mfma_f32_16x16x32_bf16(al[i], bh, acc[i][j], 0, 0, 0);
          }
        }
      }
    }
  };

  // epilogue: relu(acc+bias) -> buf0; waves 6,7 zero-fill pad cols [208,224)
  auto epi = [&](const float* __restrict__ bias) {
    __syncthreads();  // all frag reads of buf0/As complete before overwrite
#pragma unroll
    for (int i = 0; i < 2; i++)
#pragma unroll
      for (int j = 0; j < 4; j++) {
        if (j < ntile) {
#pragma unroll
          for (int r = 0; r < 4; r++) {
            int row = wm * 32 + i * 16 + quad * 4 + r;
            int col = n0col + j * 16 + ln;
            float v = acc[i][j][r] + (col < HH ? bias[col] : 0.f);
            v = fmaxf(v, 0.f);
            buf0[row * BUF_S + col] = packsplit(v);
          }
        }
      }
    if (wave >= 6) {  // wave6 rows 0..31, wave7 rows 32..63
      int rbase = (wave & 1) * 32 + quad * 8;
#pragma unroll
      for (int rr = 0; rr < 8; rr++) buf0[(rbase + rr) * BUF_S + 208 + ln] = 0u;
    }
    __syncthreads();
  };

  if (!READOUT) {
    run_layer(W1t, 96, 96, true);
    epi(b1);
    run_layer(W2t, 224, 224, false);
    epi(b2);
    run_layer(W3t, 224, 224, false);
    epi(b3);
    // ---- L4 (200->64): wave w handles col tile wn, row half wm ----
#pragma unroll
    for (int i = 0; i < 2; i++) acc[i][0] = (f32x4){0.f, 0.f, 0.f, 0.f};
    const int ct = wn;
    for (int k0 = 0; k0 < 224; k0 += 32) {
      short8b ah[2], al[2];
#pragma unroll
      for (int i = 0; i < 2; i++) {
        int r = wm * 32 + i * 16 + ln;
        const unsigned* ap = buf0 + r * BUF_S + k0 + quad * 8;
        unsigned v[8];
        *(uint4*)&v[0] = *(const uint4*)ap;
        *(uint4*)&v[4] = *(const uint4*)(ap + 4);
        unpack8(v, ah[i], al[i]);
      }
      int n = ct * 16 + ln;
      const unsigned* bp = W4t + (size_t)n * 224 + k0 + quad * 8;
      unsigned v[8];
      *(uint4*)&v[0] = *(const uint4*)bp;
      *(uint4*)&v[4] = *(const uint4*)(bp + 4);
      short8b bh, bl;
      unpack8(v, bh, bl);
#pragma unroll
      for (int i = 0; i < 2; i++) {
        acc[i][0] = __builtin_amdgcn_mfma_f32_16x16x32_bf16(ah[i], bh, acc[i][0], 0, 0, 0);
        acc[i][0] = __builtin_amdgcn_mfma_f32_16x16x32_bf16(ah[i], bl, acc[i][0], 0, 0, 0);
        acc[i][0] = __builtin_amdgcn_mfma_f32_16x16x32_bf16(al[i], bh, acc[i][0], 0, 0, 0);
      }
    }
    // x-update epilogue: x[t+1] = x[t] + 0.1*(h3@W4 + b4)  (global only, no sync)
#pragma unroll
    for (int i = 0; i < 2; i++)
#pragma unroll
      for (int r = 0; r < 4; r++) {
        int grow = bm + wm * 32 + i * 16 + quad * 4 + r;
        int col = ct * 16 + ln;
        if (grow < NN) {
          float v = acc[i][0][r] + b4[col];
          size_t base = (size_t)grow * RD;
          float old = bfp2f(xp[base + (size_t)t * ED + col]);
          xp[base + (size_t)(t + 1) * ED + col] = packsplit(old + 0.1f * v);
        }
      }
  } else {
    run_layer(W1t, 256, 256, true);
    epi(b1);
    run_layer(W2t, 224, 224, false);
    epi(b2);
    run_layer(W3t, 224, 224, false);
    epi(b3);
    // fused final layer (200->1) + molecule segment-sum: 8 threads per row
    int row = tid >> 3;
    int grow = bm + row;
    float s = 0.f;
    for (int c = (tid & 7); c < HH; c += 8) s += bfp2f(buf0[row * BUF_S + c]) * w4ro[c];
    s += __shfl_xor(s, 1, 64);
    s += __shfl_xor(s, 2, 64);
    s += __shfl_xor(s, 4, 64);
    if ((tid & 7) == 0 && grow < NN) atomicAdd(&out[mol[grow]], s + b4[0]);
  }
}

// ---------------- host launcher ----------------
extern "C" void kernel_launch(void* const* d_in, const int* in_sizes, int n_in,
                              void* d_out, int out_size, void* d_ws, size_t ws_size,
                              hipStream_t stream) {
  const int* z_i = (const int*)d_in[0];
  const int* e_src = (const int*)d_in[1];
  const int* e_snk = ((const int*)d_in[1]) + EE;
  const float* dist = (const float*)d_in[2];
  const int* mol = (const int*)d_in[3];
  const float* emb = (const float*)d_in[4];
  const float* up_bn_g = (const float*)d_in[5];
  const float* up_bn_b = (const float*)d_in[6];
  const float* up_w1 = (const float*)d_in[7];
  const float* up_b1 = (const float*)d_in[8];
  const float* up_w2 = (const float*)d_in[9];
  const float* up_b2 = (const float*)d_in[10];
  const float* up_w3 = (const float*)d_in[11];
  const float* up_b3 = (const float*)d_in[12];
  const float* up_w4 = (const float*)d_in[13];
  const float* up_b4 = (const float*)d_in[14];
  const float* ro_bn_g = (const float*)d_in[15];
  const float* ro_bn_b = (const float*)d_in[16];
  const float* ro_w1 = (const float*)d_in[17];
  const float* ro_b1 = (const float*)d_in[18];
  const float* ro_w2 = (const float*)d_in[19];
  const float* ro_b2 = (const float*)d_in[20];
  const float* ro_w3 = (const float*)d_in[21];
  const float* ro_b3 = (const float*)d_in[22];
  const float* ro_w4 = (const float*)d_in[23];
  const float* ro_b4 = (const float*)d_in[24];
  float* out = (float*)d_out;

  char* p = (char*)d_ws;
  auto alloc = [&](size_t bytes) {
    void* r = (void*)p;
    p += (bytes + 255) & ~(size_t)255;
    return r;
  };
  unsigned* x_p = (unsigned*)alloc((size_t)NN * RD * 4);   // 51.2 MB
  unsigned* m_p = (unsigned*)alloc((size_t)NN * 96 * 4);   // 19.2 MB
  int* ssink = (int*)alloc((size_t)EE * 4);
  float* sdist = (float*)alloc((size_t)EE * 4);
  int* offs = (int*)alloc((size_t)(NN + 1) * 4);
  int* deg = (int*)alloc((size_t)NN * 4);
  int* cursor = (int*)alloc((size_t)NN * 4);
  float* P = (float*)alloc((size_t)NPB2 * 512 * 4);        // 1 MB partials
  float* na = (float*)alloc(256 * 4);
  float* nb = (float*)alloc(256 * 4);
  // transposed/padded pair weights
  unsigned* w1t = (unsigned*)alloc((size_t)TT * 208 * 96 * 4);
  unsigned* w2t = (unsigned*)alloc((size_t)TT * 208 * 224 * 4);
  unsigned* w3t = (unsigned*)alloc((size_t)TT * 208 * 224 * 4);
  unsigned* w4t = (unsigned*)alloc((size_t)TT * 64 * 224 * 4);
  unsigned* r1t = (unsigned*)alloc((size_t)208 * 256 * 4);
  unsigned* r2t = (unsigned*)alloc((size_t)208 * 224 * 4);
  unsigned* r3t = (unsigned*)alloc((size_t)208 * 224 * 4);

  hipMemsetAsync(deg, 0, (size_t)NN * 4, stream);
  hipMemsetAsync(out, 0, (size_t)NMOL * 4, stream);

  WDs descs;
  descs.d[0] = {up_w1, w1t, MD, HH, 96, 208, TT};
  descs.d[1] = {up_w2, w2t, HH, HH, 224, 208, TT};
  descs.d[2] = {up_w3, w3t, HH, HH, 224, 208, TT};
  descs.d[3] = {up_w4, w4t, HH, ED, 224, 64, TT};
  descs.d[4] = {ro_w1, r1t, RD, HH, 256, 208, 1};
  descs.d[5] = {ro_w2, r2t, HH, HH, 224, 208, 1};
  descs.d[6] = {ro_w3, r3t, HH, HH, 224, 208, 1};
  wprep_kernel<<<dim3(273, 7), 256, 0, stream>>>(descs);

  emb_kernel<<<(NN * ED + 255) / 256, 256, 0, stream>>>(z_i, emb, x_p);
  hist_kernel<<<(EE + 255) / 256, 256, 0, stream>>>(e_src, deg);
  scan_kernel<<<1, 1024, 0, stream>>>(deg, offs, cursor);
  scatter_kernel<<<(EE + 255) / 256, 256, 0, stream>>>(e_src, e_snk, dist, cursor, ssink, sdist);

  const int gM = (NN + 63) / 64;  // 782

  for (int t = 0; t < TT; t++) {
    gather_kernel<<<(NN + 3) / 4, 256, 0, stream>>>(offs, ssink, sdist, x_p, t * ED, m_p);
    colstats2_kernel<96><<<NPB2, 256, 0, stream>>>(m_p, P);
    bnfinal2_kernel<<<256, 256, 0, stream>>>(P, NPB2, up_bn_g + t * MD, up_bn_b + t * MD, MD,
                                             na, nb);
    fused_kernel<false><<<gM, 512, 0, stream>>>(
        m_p, 96, na, nb,
        w1t + (size_t)t * 208 * 96, w2t + (size_t)t * 208 * 224,
        w3t + (size_t)t * 208 * 224, w4t + (size_t)t * 64 * 224,
        up_b1 + t * HH, up_b2 + t * HH, up_b3 + t * HH, up_b4 + t * ED,
        x_p, t, nullptr, nullptr, nullptr);
  }

  colstats2_kernel<256><<<NPB2, 256, 0, stream>>>(x_p, P);
  bnfinal2_kernel<<<256, 256, 0, stream>>>(P, NPB2, ro_bn_g, ro_bn_b, RD, na, nb);
  fused_kernel<true><<<gM, 512, 0, stream>>>(
      x_p, 256, na, nb,
      r1t, r2t, r3t, nullptr,
      ro_b1, ro_b2, ro_b3, ro_b4,
      nullptr, 0, ro_w4, mol, out);

  (void)in_sizes; (void)n_in; (void)out_size; (void)ws_size;
}

// Round 9
// 1094.644 us; speedup vs baseline: 1.9287x; 1.1280x over previous
//
#include <hip/hip_runtime.h>
#include <hip/hip_bf16.h>
#include <type_traits>

#define NN 50000
#define NP 50048   // NN padded to 64*782 (fused grid covers rows exactly)
#define EE 800000
#define TT 3
#define ED 64
#define NS 23
#define MD 87
#define HH 200
#define NMOL 2048
#define RD 256

#define SP 232     // LDS plane stride (shorts): 116 u32 -> balanced b128 banks
#define NPB2 512   // colstats partial blocks

typedef __attribute__((ext_vector_type(8))) short short8b;
typedef __attribute__((ext_vector_type(4))) short short4b;
typedef __attribute__((ext_vector_type(4))) float f32x4;

// ---- bf16 split helpers: value = hi + lo, each bf16 (RNE). ----
__device__ __forceinline__ unsigned short f2bf(float f) {
  unsigned u = __float_as_uint(f);
  return (unsigned short)((u + 0x7fffu + ((u >> 16) & 1u)) >> 16);
}
__device__ __forceinline__ float ubf2f(unsigned short h) {
  return __uint_as_float(((unsigned)h) << 16);
}
// interleaved pair in one u32: low16 = hi-bf16, high16 = lo-bf16
__device__ __forceinline__ float bfp2f(unsigned p) {
  return __uint_as_float(p << 16) + __uint_as_float(p & 0xffff0000u);
}
__device__ __forceinline__ unsigned packsplit(float v) {
  unsigned short h = f2bf(v);
  unsigned short l = f2bf(v - ubf2f(h));
  return (unsigned)h | ((unsigned)l << 16);
}

// ---------------- weight prep: fp32 [T][K][N] -> bf16 hi/lo planes [T][Npad][Kpad] ----
struct WD { const float* src; short* dh; short* dl; int K, N, Kpad, Npad, T; };
struct WDs { WD d[7]; };

__global__ __launch_bounds__(256) void wprep_kernel(WDs W) {
  WD w = W.d[blockIdx.y];
  int per = w.Npad * w.Kpad;
  int total = w.T * per;
  for (int idx = blockIdx.x * 256 + threadIdx.x; idx < total; idx += gridDim.x * 256) {
    int t = idx / per;
    int r = idx - t * per;
    int n = r / w.Kpad;
    int k = r - n * w.Kpad;
    float v = 0.f;
    if (k < w.K && n < w.N) v = w.src[((size_t)t * w.K + k) * w.N + n];
    unsigned short h = f2bf(v);
    unsigned short l = f2bf(v - ubf2f(h));
    w.dh[idx] = (short)h;
    w.dl[idx] = (short)l;
  }
}

// ---------------- embedding -> x slice 0 (pair) ----------------
__global__ __launch_bounds__(256) void emb_kernel(const int* __restrict__ z,
                                                  const float* __restrict__ emb,
                                                  unsigned* __restrict__ xp) {
  int idx = blockIdx.x * 256 + threadIdx.x;
  if (idx >= NN * ED) return;
  int i = idx >> 6, d = idx & 63;
  xp[(size_t)i * RD + d] = packsplit(emb[z[i] * ED + d]);
}

// ---------------- CSR build ----------------
__global__ __launch_bounds__(256) void hist_kernel(const int* __restrict__ src,
                                                   int* __restrict__ deg) {
  int e = blockIdx.x * 256 + threadIdx.x;
  if (e < EE) atomicAdd(&deg[src[e]], 1);
}

__global__ __launch_bounds__(1024) void scan_kernel(const int* __restrict__ deg,
                                                    int* __restrict__ offs,
                                                    int* __restrict__ cursor) {
  __shared__ int sh[1024];
  int tid = threadIdx.x;
  const int CH = (NN + 1023) / 1024;
  int s0 = tid * CH, s1 = s0 + CH;
  if (s1 > NN) s1 = NN;
  int sum = 0;
  for (int i = s0; i < s1; i++) sum += deg[i];
  sh[tid] = sum;
  __syncthreads();
  for (int off = 1; off < 1024; off <<= 1) {
    int t = (tid >= off) ? sh[tid - off] : 0;
    __syncthreads();
    sh[tid] += t;
    __syncthreads();
  }
  int base = sh[tid] - sum;
  for (int i = s0; i < s1; i++) {
    offs[i] = base;
    cursor[i] = base;
    base += deg[i];
  }
  if (tid == 1023) offs[NN] = sh[1023];
}

__global__ __launch_bounds__(256) void scatter_kernel(const int* __restrict__ src,
                                                      const int* __restrict__ snk,
                                                      const float* __restrict__ dist,
                                                      int* __restrict__ cursor,
                                                      int* __restrict__ ssink,
                                                      float* __restrict__ sdist) {
  int e = blockIdx.x * 256 + threadIdx.x;
  if (e >= EE) return;
  int p = atomicAdd(&cursor[src[e]], 1);
  ssink[p] = snk[e];
  sdist[p] = dist[e];
}

// ---------------- message gather: one wave per node ----------------
__global__ __launch_bounds__(256) void gather_kernel(const int* __restrict__ offs,
                                                     const int* __restrict__ ssink,
                                                     const float* __restrict__ sdist,
                                                     const unsigned* __restrict__ xp,
                                                     int toff, unsigned* __restrict__ m) {
  int node = blockIdx.x * 4 + (threadIdx.x >> 6);
  int lane = threadIdx.x & 63;
  if (node >= NN) return;
  float shift = (float)(0.8 + 0.1 * (double)lane);
  float accx = 0.f, accr = 0.f;
  int e0 = offs[node], e1 = offs[node + 1];
  for (int j = e0; j < e1; ++j) {
    int s = ssink[j];
    accx += bfp2f(xp[(size_t)s * RD + toff + lane]);
    if (lane < NS) {
      float u = sdist[j] - shift;
      accr += __expf(-u * u);
    }
  }
  if (lane < NS) m[node * 96 + lane] = packsplit(accr);
  m[node * 96 + NS + lane] = packsplit(accx);
}

// ---------------- batchnorm stats: stage 1 (vectorized, 512 blocks) ----------
template <int LD>
__global__ __launch_bounds__(256) void colstats2_kernel(const unsigned* __restrict__ X,
                                                        float* __restrict__ P) {
  constexpr int CG = LD / 4;
  constexpr int RPB = 256 / CG;
  const int t = threadIdx.x;
  const int cg = t % CG, rin = t / CG;
  float s0 = 0, s1 = 0, s2 = 0, s3 = 0, q0 = 0, q1 = 0, q2 = 0, q3 = 0;
  if (rin < RPB) {
    for (int r = blockIdx.x * RPB + rin; r < NN; r += gridDim.x * RPB) {
      uint4 v = *(const uint4*)(X + (size_t)r * LD + cg * 4);
      float f0 = bfp2f(v.x), f1 = bfp2f(v.y), f2 = bfp2f(v.z), f3 = bfp2f(v.w);
      s0 += f0; q0 += f0 * f0;
      s1 += f1; q1 += f1 * f1;
      s2 += f2; q2 += f2 * f2;
      s3 += f3; q3 += f3 * f3;
    }
  }
  __shared__ float sh[256][8];
  sh[t][0] = s0; sh[t][1] = s1; sh[t][2] = s2; sh[t][3] = s3;
  sh[t][4] = q0; sh[t][5] = q1; sh[t][6] = q2; sh[t][7] = q3;
  __syncthreads();
  if (rin == 0) {
#pragma unroll
    for (int rr = 1; rr < RPB; rr++) {
      const float* o = sh[rr * CG + cg];
      s0 += o[0]; s1 += o[1]; s2 += o[2]; s3 += o[3];
      q0 += o[4]; q1 += o[5]; q2 += o[6]; q3 += o[7];
    }
    float* Pb = P + blockIdx.x * 512;
    Pb[cg * 4 + 0] = s0; Pb[cg * 4 + 1] = s1; Pb[cg * 4 + 2] = s2; Pb[cg * 4 + 3] = s3;
    Pb[256 + cg * 4 + 0] = q0; Pb[256 + cg * 4 + 1] = q1;
    Pb[256 + cg * 4 + 2] = q2; Pb[256 + cg * 4 + 3] = q3;
  }
}

// ---------------- batchnorm stats: stage 2 (one block per column) ------------
__global__ __launch_bounds__(256) void bnfinal2_kernel(const float* __restrict__ P, int nblk,
                                                       const float* __restrict__ g,
                                                       const float* __restrict__ b, int ncols,
                                                       float* __restrict__ na,
                                                       float* __restrict__ nb) {
  int c = blockIdx.x;
  int t = threadIdx.x;
  float s = 0.f, q = 0.f;
  for (int i = t; i < nblk; i += 256) {
    s += P[i * 512 + c];
    q += P[i * 512 + 256 + c];
  }
#pragma unroll
  for (int off = 32; off > 0; off >>= 1) {
    s += __shfl_down(s, off, 64);
    q += __shfl_down(q, off, 64);
  }
  __shared__ float ws[4], wq[4];
  if ((t & 63) == 0) { ws[t >> 6] = s; wq[t >> 6] = q; }
  __syncthreads();
  if (t == 0) {
    s = ws[0] + ws[1] + ws[2] + ws[3];
    q = wq[0] + wq[1] + wq[2] + wq[3];
    if (c < ncols) {
      float mean = s / (float)NN;
      float var = q / (float)NN - mean * mean;
      float a = g[c] * rsqrtf(var + 1e-5f);
      na[c] = a;
      nb[c] = b[c] - mean * a;
    } else {
      na[c] = 0.f;  // pad cols -> BN-applied value 0
      nb[c] = 0.f;
    }
  }
}

// ---------------- BN apply: pair -> pre-normalized hi/lo bf16 planes ----------
// Rows >= NN write zeros (clean padding for the fused L1 stream).
template <int LD>
__global__ __launch_bounds__(256) void bnapply_kernel(const unsigned* __restrict__ Xp,
                                                      const float* __restrict__ na,
                                                      const float* __restrict__ nb,
                                                      short* __restrict__ Xh,
                                                      short* __restrict__ Xl) {
  int idx = blockIdx.x * 256 + threadIdx.x;  // over NP * LD/4
  if (idx >= NP * (LD / 4)) return;
  int row = idx / (LD / 4);
  int cg = (idx - row * (LD / 4)) * 4;
  short4b h, l;
  if (row < NN) {
    uint4 v = *(const uint4*)(Xp + (size_t)row * LD + cg);
    unsigned arr[4] = {v.x, v.y, v.z, v.w};
#pragma unroll
    for (int e = 0; e < 4; e++) {
      float f = bfp2f(arr[e]) * na[cg + e] + nb[cg + e];
      unsigned short hh = f2bf(f);
      h[e] = (short)hh;
      l[e] = (short)f2bf(f - ubf2f(hh));
    }
  } else {
    h = (short4b){0, 0, 0, 0};
    l = (short4b){0, 0, 0, 0};
  }
  *(short4b*)(Xh + (size_t)row * LD + cg) = h;
  *(short4b*)(Xl + (size_t)row * LD + cg) = l;
}

// ---------------- fused MLP kernel ----------------
// 64-node tile, 256 threads = 4 waves splitting N {4,3,3,3} x16; acc[4][4].
// Activations LDS-resident as hi/lo bf16 PLANES (no unpack perms); weights as
// global hi/lo planes (L2-hot). A and B software-pipelined one full k-iter
// ahead in registers -> vmcnt(N>0) waits, latency hidden. Only barrier pairs
// are the 3 epilogues. Split-precision 3-MFMA (hh,hl,lh) = fp32-equivalent.
template <bool READOUT>
__global__ __launch_bounds__(256, 2) void fused_kernel(
    const short* __restrict__ Agh, const short* __restrict__ Agl, int glda,
    const short* __restrict__ W1h, const short* __restrict__ W1l,
    const short* __restrict__ W2h, const short* __restrict__ W2l,
    const short* __restrict__ W3h, const short* __restrict__ W3l,
    const short* __restrict__ W4h, const short* __restrict__ W4l,
    const float* __restrict__ b1, const float* __restrict__ b2,
    const float* __restrict__ b3, const float* __restrict__ b4,
    unsigned* __restrict__ xp, int t,
    const float* __restrict__ w4ro, const int* __restrict__ mol,
    float* __restrict__ out) {
  __shared__ short ldsH[64 * SP];  // 29696 B
  __shared__ short ldsL[64 * SP];  // total 59392 B -> 2 blocks/CU
  const int tid = threadIdx.x;
  const int wave = tid >> 6, lane = tid & 63, ln = lane & 15, quad = lane >> 4;
  const int bm = blockIdx.x * 64;
  const int ntile = (wave == 0) ? 4 : 3;
  const int n0col = (wave == 0) ? 0 : 16 + wave * 48;  // 0, 64, 112, 160

  f32x4 acc[4][4];

  auto run_layer = [&](auto GAtag, const short* __restrict__ Wh,
                       const short* __restrict__ Wl, int Kpad, int KP) {
    constexpr bool GA = decltype(GAtag)::value;
#pragma unroll
    for (int i = 0; i < 4; i++)
#pragma unroll
      for (int j = 0; j < 4; j++) acc[i][j] = (f32x4){0.f, 0.f, 0.f, 0.f};

    short8b aph[4], apl[4], bph[4], bpl[4];
#pragma unroll
    for (int i = 0; i < 4; i++) {
      int r = i * 16 + ln;
      if constexpr (GA) {
        const size_t o = (size_t)(bm + r) * glda + quad * 8;
        aph[i] = *(const short8b*)(Agh + o);
        apl[i] = *(const short8b*)(Agl + o);
      } else {
        aph[i] = *(const short8b*)(ldsH + r * SP + quad * 8);
        apl[i] = *(const short8b*)(ldsL + r * SP + quad * 8);
      }
    }
#pragma unroll
    for (int j = 0; j < 4; j++)
      if (j < ntile) {
        const size_t o = (size_t)(n0col + j * 16 + ln) * Kpad + quad * 8;
        bph[j] = *(const short8b*)(Wh + o);
        bpl[j] = *(const short8b*)(Wl + o);
      }
    for (int k0 = 0; k0 < KP; k0 += 32) {
      short8b ah[4], al[4], bh[4], bl[4];
#pragma unroll
      for (int i = 0; i < 4; i++) { ah[i] = aph[i]; al[i] = apl[i]; }
#pragma unroll
      for (int j = 0; j < 4; j++)
        if (j < ntile) { bh[j] = bph[j]; bl[j] = bpl[j]; }
      const int kn = k0 + 32;
      if (kn < KP) {  // prefetch next k-iter (loads in flight across the MFMAs)
#pragma unroll
        for (int i = 0; i < 4; i++) {
          int r = i * 16 + ln;
          if constexpr (GA) {
            const size_t o = (size_t)(bm + r) * glda + kn + quad * 8;
            aph[i] = *(const short8b*)(Agh + o);
            apl[i] = *(const short8b*)(Agl + o);
          } else {
            aph[i] = *(const short8b*)(ldsH + r * SP + kn + quad * 8);
            apl[i] = *(const short8b*)(ldsL + r * SP + kn + quad * 8);
          }
        }
#pragma unroll
        for (int j = 0; j < 4; j++)
          if (j < ntile) {
            const size_t o = (size_t)(n0col + j * 16 + ln) * Kpad + kn + quad * 8;
            bph[j] = *(const short8b*)(Wh + o);
            bpl[j] = *(const short8b*)(Wl + o);
          }
      }
#pragma unroll
      for (int j = 0; j < 4; j++)
        if (j < ntile)
#pragma unroll
          for (int i = 0; i < 4; i++) {
            acc[i][j] = __builtin_amdgcn_mfma_f32_16x16x32_bf16(ah[i], bh[j], acc[i][j], 0, 0, 0);
            acc[i][j] = __builtin_amdgcn_mfma_f32_16x16x32_bf16(ah[i], bl[j], acc[i][j], 0, 0, 0);
            acc[i][j] = __builtin_amdgcn_mfma_f32_16x16x32_bf16(al[i], bh[j], acc[i][j], 0, 0, 0);
          }
    }
  };

  // epilogue: relu(acc+bias) -> planes; each wave zero-fills 16 pad rows' cols 208..223
  auto epi = [&](const float* __restrict__ bias) {
    __syncthreads();
#pragma unroll
    for (int i = 0; i < 4; i++)
#pragma unroll
      for (int j = 0; j < 4; j++)
        if (j < ntile)
#pragma unroll
          for (int r = 0; r < 4; r++) {
            int row = i * 16 + quad * 4 + r;
            int col = n0col + j * 16 + ln;
            float v = acc[i][j][r] + (col < HH ? bias[col] : 0.f);
            v = fmaxf(v, 0.f);
            unsigned short h = f2bf(v);
            unsigned short l = f2bf(v - ubf2f(h));
            ldsH[row * SP + col] = (short)h;
            ldsL[row * SP + col] = (short)l;
          }
    {
      int row = wave * 16 + quad * 4;
#pragma unroll
      for (int r = 0; r < 4; r++) {
        ldsH[(row + r) * SP + 208 + ln] = 0;
        ldsL[(row + r) * SP + 208 + ln] = 0;
      }
    }
    __syncthreads();
  };

  if (!READOUT) {
    run_layer(std::true_type{}, W1h, W1l, 96, 96);
    epi(b1);
    run_layer(std::false_type{}, W2h, W2l, 224, 224);
    epi(b2);
    run_layer(std::false_type{}, W3h, W3l, 224, 224);
    epi(b3);
    // ---- L4 (200->64): wave w -> cols w*16..+15, pipelined B ----
    f32x4 a4[4];
#pragma unroll
    for (int i = 0; i < 4; i++) a4[i] = (f32x4){0.f, 0.f, 0.f, 0.f};
    short8b bhp, blp;
    {
      const size_t o = (size_t)(wave * 16 + ln) * 224 + quad * 8;
      bhp = *(const short8b*)(W4h + o);
      blp = *(const short8b*)(W4l + o);
    }
    for (int k0 = 0; k0 < 224; k0 += 32) {
      short8b ah[4], al[4];
#pragma unroll
      for (int i = 0; i < 4; i++) {
        int r = i * 16 + ln;
        ah[i] = *(const short8b*)(ldsH + r * SP + k0 + quad * 8);
        al[i] = *(const short8b*)(ldsL + r * SP + k0 + quad * 8);
      }
      short8b bh = bhp, bl = blp;
      const int kn = k0 + 32;
      if (kn < 224) {
        const size_t o = (size_t)(wave * 16 + ln) * 224 + kn + quad * 8;
        bhp = *(const short8b*)(W4h + o);
        blp = *(const short8b*)(W4l + o);
      }
#pragma unroll
      for (int i = 0; i < 4; i++) {
        a4[i] = __builtin_amdgcn_mfma_f32_16x16x32_bf16(ah[i], bh, a4[i], 0, 0, 0);
        a4[i] = __builtin_amdgcn_mfma_f32_16x16x32_bf16(ah[i], bl, a4[i], 0, 0, 0);
        a4[i] = __builtin_amdgcn_mfma_f32_16x16x32_bf16(al[i], bh, a4[i], 0, 0, 0);
      }
    }
    // x-update: x[t+1] = x[t] + 0.1*(h3@W4 + b4)
#pragma unroll
    for (int i = 0; i < 4; i++)
#pragma unroll
      for (int r = 0; r < 4; r++) {
        int grow = bm + i * 16 + quad * 4 + r;
        int col = wave * 16 + ln;
        if (grow < NN) {
          float v = a4[i][r] + b4[col];
          size_t base = (size_t)grow * RD;
          float old = bfp2f(xp[base + (size_t)t * ED + col]);
          xp[base + (size_t)(t + 1) * ED + col] = packsplit(old + 0.1f * v);
        }
      }
  } else {
    run_layer(std::true_type{}, W1h, W1l, 256, 256);
    epi(b1);
    run_layer(std::false_type{}, W2h, W2l, 224, 224);
    epi(b2);
    run_layer(std::false_type{}, W3h, W3l, 224, 224);
    epi(b3);
    // fused final layer (200->1) + molecule segment-sum: 4 threads per row
    int row = tid >> 2;
    int grow = bm + row;
    float s = 0.f;
    for (int c = (tid & 3); c < HH; c += 4) {
      float v = ubf2f((unsigned short)ldsH[row * SP + c]) +
                ubf2f((unsigned short)ldsL[row * SP + c]);
      s += v * w4ro[c];
    }
    s += __shfl_xor(s, 1, 64);
    s += __shfl_xor(s, 2, 64);
    if ((tid & 3) == 0 && grow < NN) atomicAdd(&out[mol[grow]], s + b4[0]);
  }
}

// ---------------- host launcher ----------------
extern "C" void kernel_launch(void* const* d_in, const int* in_sizes, int n_in,
                              void* d_out, int out_size, void* d_ws, size_t ws_size,
                              hipStream_t stream) {
  const int* z_i = (const int*)d_in[0];
  const int* e_src = (const int*)d_in[1];
  const int* e_snk = ((const int*)d_in[1]) + EE;
  const float* dist = (const float*)d_in[2];
  const int* mol = (const int*)d_in[3];
  const float* emb = (const float*)d_in[4];
  const float* up_bn_g = (const float*)d_in[5];
  const float* up_bn_b = (const float*)d_in[6];
  const float* up_w1 = (const float*)d_in[7];
  const float* up_b1 = (const float*)d_in[8];
  const float* up_w2 = (const float*)d_in[9];
  const float* up_b2 = (const float*)d_in[10];
  const float* up_w3 = (const float*)d_in[11];
  const float* up_b3 = (const float*)d_in[12];
  const float* up_w4 = (const float*)d_in[13];
  const float* up_b4 = (const float*)d_in[14];
  const float* ro_bn_g = (const float*)d_in[15];
  const float* ro_bn_b = (const float*)d_in[16];
  const float* ro_w1 = (const float*)d_in[17];
  const float* ro_b1 = (const float*)d_in[18];
  const float* ro_w2 = (const float*)d_in[19];
  const float* ro_b2 = (const float*)d_in[20];
  const float* ro_w3 = (const float*)d_in[21];
  const float* ro_b3 = (const float*)d_in[22];
  const float* ro_w4 = (const float*)d_in[23];
  const float* ro_b4 = (const float*)d_in[24];
  float* out = (float*)d_out;

  char* p = (char*)d_ws;
  auto alloc = [&](size_t bytes) {
    void* r = (void*)p;
    p += (bytes + 255) & ~(size_t)255;
    return r;
  };
  unsigned* x_p = (unsigned*)alloc((size_t)NN * RD * 4);   // 51.2 MB pair
  unsigned* m_p = (unsigned*)alloc((size_t)NN * 96 * 4);   // 19.2 MB pair
  short* mh = (short*)alloc((size_t)NP * 96 * 2);          // BN-applied m planes
  short* ml = (short*)alloc((size_t)NP * 96 * 2);
  short* xh = (short*)alloc((size_t)NP * RD * 2);          // BN-applied x planes
  short* xl = (short*)alloc((size_t)NP * RD * 2);
  int* ssink = (int*)alloc((size_t)EE * 4);
  float* sdist = (float*)alloc((size_t)EE * 4);
  int* offs = (int*)alloc((size_t)(NN + 1) * 4);
  int* deg = (int*)alloc((size_t)NN * 4);
  int* cursor = (int*)alloc((size_t)NN * 4);
  float* P = (float*)alloc((size_t)NPB2 * 512 * 4);
  float* na = (float*)alloc(256 * 4);
  float* nb = (float*)alloc(256 * 4);
  // weight planes (transposed, padded)
  short* w1h = (short*)alloc((size_t)TT * 208 * 96 * 2);
  short* w1l = (short*)alloc((size_t)TT * 208 * 96 * 2);
  short* w2h = (short*)alloc((size_t)TT * 208 * 224 * 2);
  short* w2l = (short*)alloc((size_t)TT * 208 * 224 * 2);
  short* w3h = (short*)alloc((size_t)TT * 208 * 224 * 2);
  short* w3l = (short*)alloc((size_t)TT * 208 * 224 * 2);
  short* w4h = (short*)alloc((size_t)TT * 64 * 224 * 2);
  short* w4l = (short*)alloc((size_t)TT * 64 * 224 * 2);
  short* r1h = (short*)alloc((size_t)208 * 256 * 2);
  short* r1l = (short*)alloc((size_t)208 * 256 * 2);
  short* r2h = (short*)alloc((size_t)208 * 224 * 2);
  short* r2l = (short*)alloc((size_t)208 * 224 * 2);
  short* r3h = (short*)alloc((size_t)208 * 224 * 2);
  short* r3l = (short*)alloc((size_t)208 * 224 * 2);

  hipMemsetAsync(deg, 0, (size_t)NN * 4, stream);
  hipMemsetAsync(out, 0, (size_t)NMOL * 4, stream);

  WDs descs;
  descs.d[0] = {up_w1, w1h, w1l, MD, HH, 96, 208, TT};
  descs.d[1] = {up_w2, w2h, w2l, HH, HH, 224, 208, TT};
  descs.d[2] = {up_w3, w3h, w3l, HH, HH, 224, 208, TT};
  descs.d[3] = {up_w4, w4h, w4l, HH, ED, 224, 64, TT};
  descs.d[4] = {ro_w1, r1h, r1l, RD, HH, 256, 208, 1};
  descs.d[5] = {ro_w2, r2h, r2l, HH, HH, 224, 208, 1};
  descs.d[6] = {ro_w3, r3h, r3l, HH, HH, 224, 208, 1};
  wprep_kernel<<<dim3(546, 7), 256, 0, stream>>>(descs);

  emb_kernel<<<(NN * ED + 255) / 256, 256, 0, stream>>>(z_i, emb, x_p);
  hist_kernel<<<(EE + 255) / 256, 256, 0, stream>>>(e_src, deg);
  scan_kernel<<<1, 1024, 0, stream>>>(deg, offs, cursor);
  scatter_kernel<<<(EE + 255) / 256, 256, 0, stream>>>(e_src, e_snk, dist, cursor, ssink, sdist);

  const int gM = NP / 64;  // 782

  for (int t = 0; t < TT; t++) {
    gather_kernel<<<(NN + 3) / 4, 256, 0, stream>>>(offs, ssink, sdist, x_p, t * ED, m_p);
    colstats2_kernel<96><<<NPB2, 256, 0, stream>>>(m_p, P);
    bnfinal2_kernel<<<256, 256, 0, stream>>>(P, NPB2, up_bn_g + t * MD, up_bn_b + t * MD, MD,
                                             na, nb);
    bnapply_kernel<96><<<(NP * 24 + 255) / 256, 256, 0, stream>>>(m_p, na, nb, mh, ml);
    fused_kernel<false><<<gM, 256, 0, stream>>>(
        mh, ml, 96,
        w1h + (size_t)t * 208 * 96, w1l + (size_t)t * 208 * 96,
        w2h + (size_t)t * 208 * 224, w2l + (size_t)t * 208 * 224,
        w3h + (size_t)t * 208 * 224, w3l + (size_t)t * 208 * 224,
        w4h + (size_t)t * 64 * 224, w4l + (size_t)t * 64 * 224,
        up_b1 + t * HH, up_b2 + t * HH, up_b3 + t * HH, up_b4 + t * ED,
        x_p, t, nullptr, nullptr, nullptr);
  }

  colstats2_kernel<256><<<NPB2, 256, 0, stream>>>(x_p, P);
  bnfinal2_kernel<<<256, 256, 0, stream>>>(P, NPB2, ro_bn_g, ro_bn_b, RD, na, nb);
  bnapply_kernel<256><<<(NP * 64 + 255) / 256, 256, 0, stream>>>(x_p, na, nb, xh, xl);
  fused_kernel<true><<<gM, 256, 0, stream>>>(
      xh, xl, 256,
      r1h, r1l, r2h, r2l, r3h, r3l, nullptr, nullptr,
      ro_b1, ro_b2, ro_b3, ro_b4,
      nullptr, 0, ro_w4, mol, out);

  (void)in_sizes; (void)n_in; (void)out_size; (void)ws_size;
}

// Round 11
// 931.055 us; speedup vs baseline: 2.2676x; 1.1757x over previous
//
#include <hip/hip_runtime.h>
#include <hip/hip_bf16.h>
#include <type_traits>

#define NN 50000
#define NP 50048   // NN padded to 64*782
#define EE 800000
#define TT 3
#define ED 64
#define NS 23
#define MD 87
#define HH 200
#define NMOL 2048
#define RD 256

#define SP 216     // LDS hi-plane stride (shorts): 108 dwords = 12 mod 32 -> conflict-free b128
#define NPB2 512   // colstats partial blocks

typedef __attribute__((ext_vector_type(8))) short short8b;
typedef __attribute__((ext_vector_type(4))) short short4b;
typedef __attribute__((ext_vector_type(4))) float f32x4;

// ---- bf16 helpers ----
__device__ __forceinline__ unsigned short f2bf(float f) {
  unsigned u = __float_as_uint(f);
  return (unsigned short)((u + 0x7fffu + ((u >> 16) & 1u)) >> 16);
}
__device__ __forceinline__ float ubf2f(unsigned short h) {
  return __uint_as_float(((unsigned)h) << 16);
}
// interleaved pair in one u32: low16 = hi-bf16, high16 = lo-bf16 (fp32-equivalent)
__device__ __forceinline__ float bfp2f(unsigned p) {
  return __uint_as_float(p << 16) + __uint_as_float(p & 0xffff0000u);
}
__device__ __forceinline__ unsigned packsplit(float v) {
  unsigned short h = f2bf(v);
  unsigned short l = f2bf(v - ubf2f(h));
  return (unsigned)h | ((unsigned)l << 16);
}

// ---------------- weight prep: fp32 [T][K][N] -> bf16 hi/lo planes [T][Npad][Kpad] ----
struct WD { const float* src; short* dh; short* dl; int K, N, Kpad, Npad, T; };
struct WDs { WD d[7]; };

__global__ __launch_bounds__(256) void wprep_kernel(WDs W) {
  WD w = W.d[blockIdx.y];
  int per = w.Npad * w.Kpad;
  int total = w.T * per;
  for (int idx = blockIdx.x * 256 + threadIdx.x; idx < total; idx += gridDim.x * 256) {
    int t = idx / per;
    int r = idx - t * per;
    int n = r / w.Kpad;
    int k = r - n * w.Kpad;
    float v = 0.f;
    if (k < w.K && n < w.N) v = w.src[((size_t)t * w.K + k) * w.N + n];
    unsigned short h = f2bf(v);
    unsigned short l = f2bf(v - ubf2f(h));
    w.dh[idx] = (short)h;
    w.dl[idx] = (short)l;
  }
}

// ---------------- embedding -> x slice 0 (pair) ----------------
__global__ __launch_bounds__(256) void emb_kernel(const int* __restrict__ z,
                                                  const float* __restrict__ emb,
                                                  unsigned* __restrict__ xp) {
  int idx = blockIdx.x * 256 + threadIdx.x;
  if (idx >= NN * ED) return;
  int i = idx >> 6, d = idx & 63;
  xp[(size_t)i * RD + d] = packsplit(emb[z[i] * ED + d]);
}

// ---------------- CSR build ----------------
__global__ __launch_bounds__(256) void hist_kernel(const int* __restrict__ src,
                                                   int* __restrict__ deg) {
  int e = blockIdx.x * 256 + threadIdx.x;
  if (e < EE) atomicAdd(&deg[src[e]], 1);
}

__global__ __launch_bounds__(1024) void scan_kernel(const int* __restrict__ deg,
                                                    int* __restrict__ offs,
                                                    int* __restrict__ cursor) {
  __shared__ int sh[1024];
  int tid = threadIdx.x;
  const int CH = (NN + 1023) / 1024;
  int s0 = tid * CH, s1 = s0 + CH;
  if (s1 > NN) s1 = NN;
  int sum = 0;
  for (int i = s0; i < s1; i++) sum += deg[i];
  sh[tid] = sum;
  __syncthreads();
  for (int off = 1; off < 1024; off <<= 1) {
    int t = (tid >= off) ? sh[tid - off] : 0;
    __syncthreads();
    sh[tid] += t;
    __syncthreads();
  }
  int base = sh[tid] - sum;
  for (int i = s0; i < s1; i++) {
    offs[i] = base;
    cursor[i] = base;
    base += deg[i];
  }
  if (tid == 1023) offs[NN] = sh[1023];
}

__global__ __launch_bounds__(256) void scatter_kernel(const int* __restrict__ src,
                                                      const int* __restrict__ snk,
                                                      const float* __restrict__ dist,
                                                      int* __restrict__ cursor,
                                                      int* __restrict__ ssink,
                                                      float* __restrict__ sdist) {
  int e = blockIdx.x * 256 + threadIdx.x;
  if (e >= EE) return;
  int p = atomicAdd(&cursor[src[e]], 1);
  ssink[p] = snk[e];
  sdist[p] = dist[e];
}

// ---------------- message gather: one wave per node, 4-way unrolled ----------
__global__ __launch_bounds__(256) void gather_kernel(const int* __restrict__ offs,
                                                     const int* __restrict__ ssink,
                                                     const float* __restrict__ sdist,
                                                     const unsigned* __restrict__ xp,
                                                     int toff, unsigned* __restrict__ m) {
  int node = blockIdx.x * 4 + (threadIdx.x >> 6);
  int lane = threadIdx.x & 63;
  if (node >= NN) return;
  float shift = (float)(0.8 + 0.1 * (double)lane);
  int e0 = offs[node], e1 = offs[node + 1];
  float ax0 = 0.f, ax1 = 0.f, ar0 = 0.f, ar1 = 0.f;
  int j = e0;
  for (; j + 4 <= e1; j += 4) {
    int s0 = ssink[j], s1 = ssink[j + 1], s2 = ssink[j + 2], s3 = ssink[j + 3];
    float d0 = sdist[j], d1 = sdist[j + 1], d2 = sdist[j + 2], d3 = sdist[j + 3];
    float x0 = bfp2f(xp[(size_t)s0 * RD + toff + lane]);
    float x1 = bfp2f(xp[(size_t)s1 * RD + toff + lane]);
    float x2 = bfp2f(xp[(size_t)s2 * RD + toff + lane]);
    float x3 = bfp2f(xp[(size_t)s3 * RD + toff + lane]);
    ax0 += x0 + x2;
    ax1 += x1 + x3;
    if (lane < NS) {
      float u0 = d0 - shift, u1 = d1 - shift, u2 = d2 - shift, u3 = d3 - shift;
      ar0 += __expf(-u0 * u0) + __expf(-u2 * u2);
      ar1 += __expf(-u1 * u1) + __expf(-u3 * u3);
    }
  }
  for (; j < e1; j++) {
    int s = ssink[j];
    float d = sdist[j];
    ax0 += bfp2f(xp[(size_t)s * RD + toff + lane]);
    if (lane < NS) {
      float u = d - shift;
      ar0 += __expf(-u * u);
    }
  }
  float accx = ax0 + ax1, accr = ar0 + ar1;
  if (lane < NS) m[node * 96 + lane] = packsplit(accr);
  m[node * 96 + NS + lane] = packsplit(accx);
}

// ---------------- batchnorm stats: stage 1 (vectorized, 512 blocks) ----------
template <int LD>
__global__ __launch_bounds__(256) void colstats2_kernel(const unsigned* __restrict__ X,
                                                        float* __restrict__ P) {
  constexpr int CG = LD / 4;
  constexpr int RPB = 256 / CG;
  const int t = threadIdx.x;
  const int cg = t % CG, rin = t / CG;
  float s0 = 0, s1 = 0, s2 = 0, s3 = 0, q0 = 0, q1 = 0, q2 = 0, q3 = 0;
  if (rin < RPB) {
    for (int r = blockIdx.x * RPB + rin; r < NN; r += gridDim.x * RPB) {
      uint4 v = *(const uint4*)(X + (size_t)r * LD + cg * 4);
      float f0 = bfp2f(v.x), f1 = bfp2f(v.y), f2 = bfp2f(v.z), f3 = bfp2f(v.w);
      s0 += f0; q0 += f0 * f0;
      s1 += f1; q1 += f1 * f1;
      s2 += f2; q2 += f2 * f2;
      s3 += f3; q3 += f3 * f3;
    }
  }
  __shared__ float sh[256][8];
  sh[t][0] = s0; sh[t][1] = s1; sh[t][2] = s2; sh[t][3] = s3;
  sh[t][4] = q0; sh[t][5] = q1; sh[t][6] = q2; sh[t][7] = q3;
  __syncthreads();
  if (rin == 0) {
#pragma unroll
    for (int rr = 1; rr < RPB; rr++) {
      const float* o = sh[rr * CG + cg];
      s0 += o[0]; s1 += o[1]; s2 += o[2]; s3 += o[3];
      q0 += o[4]; q1 += o[5]; q2 += o[6]; q3 += o[7];
    }
    float* Pb = P + blockIdx.x * 512;
    Pb[cg * 4 + 0] = s0; Pb[cg * 4 + 1] = s1; Pb[cg * 4 + 2] = s2; Pb[cg * 4 + 3] = s3;
    Pb[256 + cg * 4 + 0] = q0; Pb[256 + cg * 4 + 1] = q1;
    Pb[256 + cg * 4 + 2] = q2; Pb[256 + cg * 4 + 3] = q3;
  }
}

// ---------------- batchnorm stats: stage 2 (one block per column) ------------
__global__ __launch_bounds__(256) void bnfinal2_kernel(const float* __restrict__ P, int nblk,
                                                       const float* __restrict__ g,
                                                       const float* __restrict__ b, int ncols,
                                                       float* __restrict__ na,
                                                       float* __restrict__ nb) {
  int c = blockIdx.x;
  int t = threadIdx.x;
  float s = 0.f, q = 0.f;
  for (int i = t; i < nblk; i += 256) {
    s += P[i * 512 + c];
    q += P[i * 512 + 256 + c];
  }
#pragma unroll
  for (int off = 32; off > 0; off >>= 1) {
    s += __shfl_down(s, off, 64);
    q += __shfl_down(q, off, 64);
  }
  __shared__ float ws[4], wq[4];
  if ((t & 63) == 0) { ws[t >> 6] = s; wq[t >> 6] = q; }
  __syncthreads();
  if (t == 0) {
    s = ws[0] + ws[1] + ws[2] + ws[3];
    q = wq[0] + wq[1] + wq[2] + wq[3];
    if (c < ncols) {
      float mean = s / (float)NN;
      float var = q / (float)NN - mean * mean;
      float a = g[c] * rsqrtf(var + 1e-5f);
      na[c] = a;
      nb[c] = b[c] - mean * a;
    } else {
      na[c] = 0.f;  // pad cols -> BN-applied value 0
      nb[c] = 0.f;
    }
  }
}

// ---------------- BN apply: pair -> pre-normalized bf16 hi plane only --------
// (2-term split-precision: A-side lo residual dropped; rows >= NN write zeros.)
template <int LD>
__global__ __launch_bounds__(256) void bnapply_kernel(const unsigned* __restrict__ Xp,
                                                      const float* __restrict__ na,
                                                      const float* __restrict__ nb,
                                                      short* __restrict__ Xh) {
  int idx = blockIdx.x * 256 + threadIdx.x;  // over NP * LD/4
  if (idx >= NP * (LD / 4)) return;
  int row = idx / (LD / 4);
  int cg = (idx - row * (LD / 4)) * 4;
  short4b h;
  if (row < NN) {
    uint4 v = *(const uint4*)(Xp + (size_t)row * LD + cg);
    unsigned arr[4] = {v.x, v.y, v.z, v.w};
#pragma unroll
    for (int e = 0; e < 4; e++) {
      float f = bfp2f(arr[e]) * na[cg + e] + nb[cg + e];
      h[e] = (short)f2bf(f);
    }
  } else {
    h = (short4b){0, 0, 0, 0};
  }
  *(short4b*)(Xh + (size_t)row * LD + cg) = h;
}

// ---------------- fused MLP kernel ----------------
// 64-node tile, 4 waves splitting N {4,3,3,3}x16, acc[4][4]. Activations in LDS
// as a single bf16 hi plane (27.7 KB -> 4 blocks/CU at VGPR<=128 = 16 waves/CU).
// Weights = global hi/lo planes (L2-hot). 2-term split precision:
// acc += ah*bh + ah*bl (error ~2^-9 rel). K-loops fully unrolled.
// K-overread discipline (R10 bug fix): cols [208,216) of EVERY row are zeroed
// in each epilogue -- uninitialized LDS can be NaN-patterned and NaN*0=NaN in
// MFMA; the k in [216,224) overlap reads the next row's finite activations
// (x zero-padded B) and row 63's overlap hits the zeroed 16-short tail.
template <bool READOUT>
__global__ __launch_bounds__(256, 4) void fused_kernel(
    const short* __restrict__ Agh, int glda,
    const short* __restrict__ W1h, const short* __restrict__ W1l,
    const short* __restrict__ W2h, const short* __restrict__ W2l,
    const short* __restrict__ W3h, const short* __restrict__ W3l,
    const short* __restrict__ W4h, const short* __restrict__ W4l,
    const float* __restrict__ b1, const float* __restrict__ b2,
    const float* __restrict__ b3, const float* __restrict__ b4,
    unsigned* __restrict__ xp, int t,
    const float* __restrict__ w4ro, const int* __restrict__ mol,
    float* __restrict__ out) {
  __shared__ short ldsH[64 * SP + 16];
  const int tid = threadIdx.x;
  const int wave = tid >> 6, lane = tid & 63, ln = lane & 15, quad = lane >> 4;
  const int bm = blockIdx.x * 64;
  const int ntile = (wave == 0) ? 4 : 3;
  const int n0col = (wave == 0) ? 0 : 16 + wave * 48;  // 0, 64, 112, 160

  if (tid < 16) ldsH[64 * SP + tid] = 0;  // zero tail for row-63 k-overread

  f32x4 acc[4][4];

  auto layer = [&](auto kp_tag, auto ga_tag, const short* __restrict__ Wh,
                   const short* __restrict__ Wl, int Kpad) {
    constexpr int KP = decltype(kp_tag)::value;
    constexpr bool GA = decltype(ga_tag)::value;
#pragma unroll
    for (int i = 0; i < 4; i++)
#pragma unroll
      for (int j = 0; j < 4; j++) acc[i][j] = (f32x4){0.f, 0.f, 0.f, 0.f};
#pragma unroll
    for (int k0 = 0; k0 < KP; k0 += 32) {
      short8b ah[4], bh[4], bl[4];
#pragma unroll
      for (int i = 0; i < 4; i++) {
        int r = i * 16 + ln;
        if constexpr (GA)
          ah[i] = *(const short8b*)(Agh + (size_t)(bm + r) * glda + k0 + quad * 8);
        else
          ah[i] = *(const short8b*)(ldsH + r * SP + k0 + quad * 8);
      }
#pragma unroll
      for (int j = 0; j < 4; j++)
        if (j < ntile) {
          const size_t o = (size_t)(n0col + j * 16 + ln) * Kpad + k0 + quad * 8;
          bh[j] = *(const short8b*)(Wh + o);
          bl[j] = *(const short8b*)(Wl + o);
        }
#pragma unroll
      for (int j = 0; j < 4; j++)
        if (j < ntile)
#pragma unroll
          for (int i = 0; i < 4; i++) {
            acc[i][j] = __builtin_amdgcn_mfma_f32_16x16x32_bf16(ah[i], bh[j], acc[i][j], 0, 0, 0);
            acc[i][j] = __builtin_amdgcn_mfma_f32_16x16x32_bf16(ah[i], bl[j], acc[i][j], 0, 0, 0);
          }
    }
  };

  // epilogue: relu(acc+bias) -> hi plane; zero cols [208,216) of every row
  auto epi = [&](const float* __restrict__ bias) {
    __syncthreads();
#pragma unroll
    for (int i = 0; i < 4; i++)
#pragma unroll
      for (int j = 0; j < 4; j++)
        if (j < ntile)
#pragma unroll
          for (int r = 0; r < 4; r++) {
            int row = i * 16 + quad * 4 + r;
            int col = n0col + j * 16 + ln;
            float v = acc[i][j][r] + (col < HH ? bias[col] : 0.f);
            v = fmaxf(v, 0.f);
            ldsH[row * SP + col] = (short)f2bf(v);
          }
    {  // NaN guard: cols 208..215 (4 threads/row x 1 dword)
      int row = tid >> 2;
      *(int*)(ldsH + row * SP + 208 + (tid & 3) * 2) = 0;
    }
    __syncthreads();
  };

  if (!READOUT) {
    layer(std::integral_constant<int, 96>{}, std::true_type{}, W1h, W1l, 96);
    epi(b1);
    layer(std::integral_constant<int, 224>{}, std::false_type{}, W2h, W2l, 224);
    epi(b2);
    layer(std::integral_constant<int, 224>{}, std::false_type{}, W3h, W3l, 224);
    epi(b3);
    // ---- L4 (200->64): wave w -> cols w*16..+15 ----
    f32x4 a4[4];
#pragma unroll
    for (int i = 0; i < 4; i++) a4[i] = (f32x4){0.f, 0.f, 0.f, 0.f};
#pragma unroll
    for (int k0 = 0; k0 < 224; k0 += 32) {
      short8b ah[4], bh, bl;
#pragma unroll
      for (int i = 0; i < 4; i++) {
        int r = i * 16 + ln;
        ah[i] = *(const short8b*)(ldsH + r * SP + k0 + quad * 8);
      }
      const size_t o = (size_t)(wave * 16 + ln) * 224 + k0 + quad * 8;
      bh = *(const short8b*)(W4h + o);
      bl = *(const short8b*)(W4l + o);
#pragma unroll
      for (int i = 0; i < 4; i++) {
        a4[i] = __builtin_amdgcn_mfma_f32_16x16x32_bf16(ah[i], bh, a4[i], 0, 0, 0);
        a4[i] = __builtin_amdgcn_mfma_f32_16x16x32_bf16(ah[i], bl, a4[i], 0, 0, 0);
      }
    }
    // x-update: x[t+1] = x[t] + 0.1*(h3@W4 + b4)  (x stays fp32-equivalent pair)
#pragma unroll
    for (int i = 0; i < 4; i++)
#pragma unroll
      for (int r = 0; r < 4; r++) {
        int grow = bm + i * 16 + quad * 4 + r;
        int col = wave * 16 + ln;
        if (grow < NN) {
          float v = a4[i][r] + b4[col];
          size_t base = (size_t)grow * RD;
          float old = bfp2f(xp[base + (size_t)t * ED + col]);
          xp[base + (size_t)(t + 1) * ED + col] = packsplit(old + 0.1f * v);
        }
      }
  } else {
    layer(std::integral_constant<int, 256>{}, std::true_type{}, W1h, W1l, 256);
    epi(b1);
    layer(std::integral_constant<int, 224>{}, std::false_type{}, W2h, W2l, 224);
    epi(b2);
    layer(std::integral_constant<int, 224>{}, std::false_type{}, W3h, W3l, 224);
    epi(b3);
    // fused final layer (200->1) + molecule segment-sum: 4 threads per row
    int row = tid >> 2;
    int grow = bm + row;
    float s = 0.f;
    for (int c = (tid & 3); c < HH; c += 4)
      s += ubf2f((unsigned short)ldsH[row * SP + c]) * w4ro[c];
    s += __shfl_xor(s, 1, 64);
    s += __shfl_xor(s, 2, 64);
    if ((tid & 3) == 0 && grow < NN) atomicAdd(&out[mol[grow]], s + b4[0]);
  }
}

// ---------------- host launcher ----------------
extern "C" void kernel_launch(void* const* d_in, const int* in_sizes, int n_in,
                              void* d_out, int out_size, void* d_ws, size_t ws_size,
                              hipStream_t stream) {
  const int* z_i = (const int*)d_in[0];
  const int* e_src = (const int*)d_in[1];
  const int* e_snk = ((const int*)d_in[1]) + EE;
  const float* dist = (const float*)d_in[2];
  const int* mol = (const int*)d_in[3];
  const float* emb = (const float*)d_in[4];
  const float* up_bn_g = (const float*)d_in[5];
  const float* up_bn_b = (const float*)d_in[6];
  const float* up_w1 = (const float*)d_in[7];
  const float* up_b1 = (const float*)d_in[8];
  const float* up_w2 = (const float*)d_in[9];
  const float* up_b2 = (const float*)d_in[10];
  const float* up_w3 = (const float*)d_in[11];
  const float* up_b3 = (const float*)d_in[12];
  const float* up_w4 = (const float*)d_in[13];
  const float* up_b4 = (const float*)d_in[14];
  const float* ro_bn_g = (const float*)d_in[15];
  const float* ro_bn_b = (const float*)d_in[16];
  const float* ro_w1 = (const float*)d_in[17];
  const float* ro_b1 = (const float*)d_in[18];
  const float* ro_w2 = (const float*)d_in[19];
  const float* ro_b2 = (const float*)d_in[20];
  const float* ro_w3 = (const float*)d_in[21];
  const float* ro_b3 = (const float*)d_in[22];
  const float* ro_w4 = (const float*)d_in[23];
  const float* ro_b4 = (const float*)d_in[24];
  float* out = (float*)d_out;

  char* p = (char*)d_ws;
  auto alloc = [&](size_t bytes) {
    void* r = (void*)p;
    p += (bytes + 255) & ~(size_t)255;
    return r;
  };
  unsigned* x_p = (unsigned*)alloc((size_t)NN * RD * 4);   // fp32-equiv pair
  unsigned* m_p = (unsigned*)alloc((size_t)NN * 96 * 4);
  short* mh = (short*)alloc((size_t)NP * 96 * 2);          // BN-applied m hi plane
  short* xh = (short*)alloc((size_t)NP * RD * 2);          // BN-applied x hi plane
  int* ssink = (int*)alloc((size_t)EE * 4);
  float* sdist = (float*)alloc((size_t)EE * 4);
  int* offs = (int*)alloc((size_t)(NN + 1) * 4);
  int* deg = (int*)alloc((size_t)NN * 4);
  int* cursor = (int*)alloc((size_t)NN * 4);
  float* P = (float*)alloc((size_t)NPB2 * 512 * 4);
  float* na = (float*)alloc(256 * 4);
  float* nb = (float*)alloc(256 * 4);
  // weight planes (transposed, padded)
  short* w1h = (short*)alloc((size_t)TT * 208 * 96 * 2);
  short* w1l = (short*)alloc((size_t)TT * 208 * 96 * 2);
  short* w2h = (short*)alloc((size_t)TT * 208 * 224 * 2);
  short* w2l = (short*)alloc((size_t)TT * 208 * 224 * 2);
  short* w3h = (short*)alloc((size_t)TT * 208 * 224 * 2);
  short* w3l = (short*)alloc((size_t)TT * 208 * 224 * 2);
  short* w4h = (short*)alloc((size_t)TT * 64 * 224 * 2);
  short* w4l = (short*)alloc((size_t)TT * 64 * 224 * 2);
  short* r1h = (short*)alloc((size_t)208 * 256 * 2);
  short* r1l = (short*)alloc((size_t)208 * 256 * 2);
  short* r2h = (short*)alloc((size_t)208 * 224 * 2);
  short* r2l = (short*)alloc((size_t)208 * 224 * 2);
  short* r3h = (short*)alloc((size_t)208 * 224 * 2);
  short* r3l = (short*)alloc((size_t)208 * 224 * 2);

  hipMemsetAsync(deg, 0, (size_t)NN * 4, stream);
  hipMemsetAsync(out, 0, (size_t)NMOL * 4, stream);

  WDs descs;
  descs.d[0] = {up_w1, w1h, w1l, MD, HH, 96, 208, TT};
  descs.d[1] = {up_w2, w2h, w2l, HH, HH, 224, 208, TT};
  descs.d[2] = {up_w3, w3h, w3l, HH, HH, 224, 208, TT};
  descs.d[3] = {up_w4, w4h, w4l, HH, ED, 224, 64, TT};
  descs.d[4] = {ro_w1, r1h, r1l, RD, HH, 256, 208, 1};
  descs.d[5] = {ro_w2, r2h, r2l, HH, HH, 224, 208, 1};
  descs.d[6] = {ro_w3, r3h, r3l, HH, HH, 224, 208, 1};
  wprep_kernel<<<dim3(546, 7), 256, 0, stream>>>(descs);

  emb_kernel<<<(NN * ED + 255) / 256, 256, 0, stream>>>(z_i, emb, x_p);
  hist_kernel<<<(EE + 255) / 256, 256, 0, stream>>>(e_src, deg);
  scan_kernel<<<1, 1024, 0, stream>>>(deg, offs, cursor);
  scatter_kernel<<<(EE + 255) / 256, 256, 0, stream>>>(e_src, e_snk, dist, cursor, ssink, sdist);

  const int gM = NP / 64;  // 782

  for (int t = 0; t < TT; t++) {
    gather_kernel<<<(NN + 3) / 4, 256, 0, stream>>>(offs, ssink, sdist, x_p, t * ED, m_p);
    colstats2_kernel<96><<<NPB2, 256, 0, stream>>>(m_p, P);
    bnfinal2_kernel<<<256, 256, 0, stream>>>(P, NPB2, up_bn_g + t * MD, up_bn_b + t * MD, MD,
                                             na, nb);
    bnapply_kernel<96><<<(NP * 24 + 255) / 256, 256, 0, stream>>>(m_p, na, nb, mh);
    fused_kernel<false><<<gM, 256, 0, stream>>>(
        mh, 96,
        w1h + (size_t)t * 208 * 96, w1l + (size_t)t * 208 * 96,
        w2h + (size_t)t * 208 * 224, w2l + (size_t)t * 208 * 224,
        w3h + (size_t)t * 208 * 224, w3l + (size_t)t * 208 * 224,
        w4h + (size_t)t * 64 * 224, w4l + (size_t)t * 64 * 224,
        up_b1 + t * HH, up_b2 + t * HH, up_b3 + t * HH, up_b4 + t * ED,
        x_p, t, nullptr, nullptr, nullptr);
  }

  colstats2_kernel<256><<<NPB2, 256, 0, stream>>>(x_p, P);
  bnfinal2_kernel<<<256, 256, 0, stream>>>(P, NPB2, ro_bn_g, ro_bn_b, RD, na, nb);
  bnapply_kernel<256><<<(NP * 64 + 255) / 256, 256, 0, stream>>>(x_p, na, nb, xh);
  fused_kernel<true><<<gM, 256, 0, stream>>>(
      xh, 256,
      r1h, r1l, r2h, r2l, r3h, r3l, nullptr, nullptr,
      ro_b1, ro_b2, ro_b3, ro_b4,
      nullptr, 0, ro_w4, mol, out);

  (void)in_sizes; (void)n_in; (void)out_size; (void)ws_size;
}